// Round 15
// baseline (330.934 us; speedup 1.0000x reference)
//
#include <hip/hip_runtime.h>
#include <hip/hip_bf16.h>
#include <math.h>

typedef __hip_bfloat16 bf16;
typedef unsigned short u16;
typedef __attribute__((ext_vector_type(8))) short short8;
typedef __attribute__((ext_vector_type(4))) float f32x4;

#define NB      8
#define SEQ     1024
#define EDIM    512
#define E2DIM   1024
#define ROWS    8192
#define INV_SQRT_E 0.04419417382415922f
#define ATT_SCL    0.06375985678148161f   /* INV_SQRT_E * log2(e) */

__device__ inline u16 f2bu(float f) {           // fp32 -> bf16 bits, RNE
    union { float f; unsigned u; } c; c.f = f;
    return (u16)((c.u + 0x7FFF + ((c.u >> 16) & 1)) >> 16);
}

__device__ __forceinline__ unsigned cvtpk_bf16(float lo, float hi) {
    unsigned r;
    asm("v_cvt_pk_bf16_f32 %0, %1, %2" : "=v"(r) : "v"(lo), "v"(hi));
    return r;
}

// counted-vmcnt pipeline fence (T4): loads stay in flight across barriers.
#define VMCNT(N) do { \
    asm volatile("s_waitcnt vmcnt(" #N ")" ::: "memory"); \
    __builtin_amdgcn_sched_barrier(0); \
    __builtin_amdgcn_s_barrier(); \
    __builtin_amdgcn_sched_barrier(0); } while (0)

__device__ __forceinline__ void dma16(const u16* g, u16* l) {
    __builtin_amdgcn_global_load_lds(
        (const __attribute__((address_space(1))) void*)g,
        (__attribute__((address_space(3))) void*)l, 16, 0, 0);
}

// ---------------------------------------------------------------------------
// Input dtype autodetect (proved inputs are fp32; kept as cheap insurance).
// ---------------------------------------------------------------------------
__global__ __launch_bounds__(256) void detect_dtype(const u16* __restrict__ x,
                                                    int* __restrict__ flag) {
    int t = threadIdx.x;
    int cnt = 0;
    for (int k = t; k < 8192; k += 256) {
        int e = (x[k] >> 7) & 0xFF;
        if (e >= 0xC0) cnt++;
    }
#pragma unroll
    for (int o = 32; o > 0; o >>= 1) cnt += __shfl_xor(cnt, o);
    __shared__ int red[4];
    if ((t & 63) == 0) red[t >> 6] = cnt;
    __syncthreads();
    if (t == 0) flag[0] = (red[0] + red[1] + red[2] + red[3] > 100) ? 1 : 0;
}

// ---------------------------------------------------------------------------
// Batch conversion of all 23 inputs -> fp32 workspace (dtype-adaptive).
// ---------------------------------------------------------------------------
struct CvtBatch {
    const void* src[23];
    float4*     dst[23];
    int         pre4[24];
};

__global__ __launch_bounds__(256) void cvt_all(CvtBatch a, int total4,
                                               const int* __restrict__ flag) {
    int t = blockIdx.x * 256 + threadIdx.x;
    if (t >= total4) return;
    int lo = 0;
    while (t >= a.pre4[lo + 1]) lo++;
    int li = t - a.pre4[lo];
    if (flag[0]) {
        a.dst[lo][li] = ((const float4*)a.src[lo])[li];
    } else {
        ushort4 u = ((const ushort4*)a.src[lo])[li];
        union { unsigned int i; float f; } c;
        float4 o;
        c.i = ((unsigned)u.x) << 16; o.x = c.f;
        c.i = ((unsigned)u.y) << 16; o.y = c.f;
        c.i = ((unsigned)u.z) << 16; o.z = c.f;
        c.i = ((unsigned)u.w) << 16; o.w = c.f;
        a.dst[lo][li] = o;
    }
}

// fp32 -> bf16 elementwise, n/4 threads
__global__ __launch_bounds__(256) void f2b_kernel(const float* __restrict__ src,
                                                  u16* __restrict__ dst, int n4) {
    int i = blockIdx.x * 256 + threadIdx.x;
    if (i >= n4) return;
    float4 a = ((const float4*)src)[i];
    ushort4 o;
    o.x = f2bu(a.x); o.y = f2bu(a.y); o.z = f2bu(a.z); o.w = f2bu(a.w);
    ((ushort4*)dst)[i] = o;
}

#define LDK 32   /* linear LDS row: 32 bf16 = 64 B = 4 chunks of 16 B */

// Bijective XCD-aware block swizzle (requires gridDim.x*gridDim.y % 8 == 0).
__device__ __forceinline__ void xcd_swz(int& bx, int& by) {
    const int nx  = gridDim.x;
    const int nwg = nx * gridDim.y;
    const int lid = blockIdx.y * nx + blockIdx.x;
    const int q   = nwg >> 3;
    const int s   = (lid & 7) * q + (lid >> 3);
    bx = s % nx;
    by = s / nx;
}

// ---------------------------------------------------------------------------
// Fold batch: 6 spectral layers, z-indexed kernels (3 launches total).
// ---------------------------------------------------------------------------
struct FoldBatch {
    const float* w[6];
    const float* fw[6];
    u16* t1[6];
    u16* t2[6];
    u16* mt[6];
    int  n[6], lg[6];
    float sc[6];
};

__global__ __launch_bounds__(256) void fold_trconv(FoldBatch fb) {
    const int z = blockIdx.z;
    const int n = fb.n[z];
    const int bx = blockIdx.x * 32, by = blockIdx.y * 32;
    if (bx >= n || by >= n) return;
    __shared__ float t[32][33];
    const int tx = threadIdx.x & 31, ty = threadIdx.x >> 5;   // 32x8
    const float* src = fb.fw[z];
    u16* dst = fb.t1[z];
#pragma unroll
    for (int r = 0; r < 32; r += 8)
        t[ty + r][tx] = src[(size_t)(by + ty + r) * n + bx + tx];
    __syncthreads();
#pragma unroll
    for (int r = 0; r < 32; r += 8)
        dst[(size_t)(bx + ty + r) * n + by + tx] = f2bu(t[tx][ty + r]);
}

__global__ __launch_bounds__(256) void fold_circ(FoldBatch fb) {
    const int z = blockIdx.z;
    const int n = fb.n[z], lg = fb.lg[z];
    int idx = blockIdx.x * 256 + threadIdx.x;
    if (idx >= n * n) return;
    int mask = n - 1;
    int m = idx & mask;
    int j = idx >> lg;
    fb.t2[z][idx] = f2bu(fb.w[z][(m - j) & mask]);
}

// 3-buffer single-barrier pipeline, hoisted staging addresses.
__global__ __launch_bounds__(256) void fold_gemm(FoldBatch fb) {
    const int z = blockIdx.z;
    const int n = fb.n[z];
    const int bm = blockIdx.y * 128, bn = blockIdx.x * 128;
    if (bm >= n || bn >= n) return;
    const u16* A  = fb.t1[z];
    const u16* Bt = fb.t2[z];
    u16* Mt = fb.mt[z];
    const float scale = fb.sc[z];

    __shared__ u16 Asl[3][128 * LDK];
    __shared__ u16 Bsl[3][128 * LDK];
    const int tid = threadIdx.x;
    const int lane = tid & 63, wave = tid >> 6;
    const int wy = wave >> 1, wx = wave & 1;
    const int qd = lane >> 4, ln16 = lane & 15;
    const int ca = (qd ^ ((ln16 >> 1) & 3)) * 8;   // swizzled read chunk

    const int srow = wave * 16 + (lane >> 2);
    const int scol = ((lane & 3) ^ ((lane >> 3) & 3)) * 8;
    const int lo   = wave * 16 * LDK;
    const size_t a64 = (size_t)64 * n;
    const u16* pA = A  + (size_t)bm * n + (size_t)srow * n + scol;
    const u16* pB = Bt + (size_t)bn * n + (size_t)srow * n + scol;

    f32x4 acc[4][4];
#pragma unroll
    for (int i = 0; i < 4; i++)
#pragma unroll
        for (int j = 0; j < 4; j++)
#pragma unroll
            for (int r = 0; r < 4; r++) acc[i][j][r] = 0.f;

#define STAGE_FG(bi) do { \
    dma16(pA,       &Asl[bi][lo]); \
    dma16(pA + a64, &Asl[bi][lo + 64 * LDK]); \
    dma16(pB,       &Bsl[bi][lo]); \
    dma16(pB + a64, &Bsl[bi][lo + 64 * LDK]); \
    pA += 32; pB += 32; } while (0)

    const int nt = n >> 5;
    STAGE_FG(0);
    STAGE_FG(1);
    int cur = 0, stg = 2;
    for (int t = 0; t < nt; ++t) {
        if (t < nt - 1) { VMCNT(4); } else { VMCNT(0); }
        const u16* Ac = Asl[cur];
        const u16* Bc = Bsl[cur];
        short8 af[4], bf_[4];
#pragma unroll
        for (int i = 0; i < 4; i++) {
            af[i]  = *(const short8*)&Ac[(wy * 64 + i * 16 + ln16) * LDK + ca];
            bf_[i] = *(const short8*)&Bc[(wx * 64 + i * 16 + ln16) * LDK + ca];
        }
        if (t + 2 < nt) STAGE_FG(stg);
#pragma unroll
        for (int i = 0; i < 4; i++)
#pragma unroll
            for (int j = 0; j < 4; j++)
                acc[i][j] = __builtin_amdgcn_mfma_f32_16x16x32_bf16(af[i], bf_[j], acc[i][j], 0, 0, 0);
        cur = (cur == 2) ? 0 : cur + 1;
        stg = (stg == 2) ? 0 : stg + 1;
    }
#undef STAGE_FG
#pragma unroll
    for (int i = 0; i < 4; i++)
#pragma unroll
        for (int j = 0; j < 4; j++) {
            const int col = bn + wx * 64 + j * 16 + ln16;
#pragma unroll
            for (int r = 0; r < 4; r++) {
                const int row = bm + wy * 64 + i * 16 + qd * 4 + r;
                Mt[(size_t)row * n + col] = f2bu(acc[i][j][r] * scale);
            }
        }
}

// ---------------------------------------------------------------------------
// bf16 MFMA GEMM (single B): C = act( A @ B + bias ). B pre-transposed.
// 128x64 tile, BK=32, 3-buffer single-barrier pipeline, swizzled LDS.
// ---------------------------------------------------------------------------
__global__ __launch_bounds__(256) void gemm_bf(
    const u16* __restrict__ A, int lda,
    const u16* __restrict__ Bt, int ldb,
    const float* __restrict__ bias,
    float* __restrict__ Cf, int ldc,
    u16* __restrict__ Cb, int ldcb,
    u16* __restrict__ Cb2, int ldcb2,
    const float* __restrict__ aux, int ldaux,
    int K, int mode)
{
    __shared__ u16 Asl[3][128 * LDK];
    __shared__ u16 Bsl[3][64 * LDK];
    const int tid = threadIdx.x;
    int bxs, bys;
    xcd_swz(bxs, bys);
    const int bm = bys * 128, bn = bxs * 64;
    const int lane = tid & 63, wave = tid >> 6;
    const int wy = wave >> 1, wx = wave & 1;
    const int qd = lane >> 4, ln16 = lane & 15;
    const int ca = (qd ^ ((ln16 >> 1) & 3)) * 8;

    const int srow = wave * 16 + (lane >> 2);
    const int scol = ((lane & 3) ^ ((lane >> 3) & 3)) * 8;
    const int lo   = wave * 16 * LDK;
    const size_t a64 = (size_t)64 * lda;
    const u16* pA = A  + (size_t)bm * lda + (size_t)srow * lda + scol;
    const u16* pB = Bt + (size_t)bn * ldb + (size_t)srow * ldb + scol;

    f32x4 acc[4][2];
#pragma unroll
    for (int i = 0; i < 4; i++)
#pragma unroll
        for (int j = 0; j < 2; j++)
#pragma unroll
            for (int r = 0; r < 4; r++) acc[i][j][r] = 0.f;

#define STAGE_GB(bi) do { \
    dma16(pA,       &Asl[bi][lo]); \
    dma16(pA + a64, &Asl[bi][lo + 64 * LDK]); \
    dma16(pB,       &Bsl[bi][lo]); \
    pA += 32; pB += 32; } while (0)

    const int nt = K >> 5;
    STAGE_GB(0);
    STAGE_GB(1);
    int cur = 0, stg = 2;
    for (int t = 0; t < nt; ++t) {
        if (t < nt - 1) { VMCNT(3); } else { VMCNT(0); }
        const u16* Ac = Asl[cur];
        const u16* Bc = Bsl[cur];
        short8 af[4], bf_[2];
#pragma unroll
        for (int i = 0; i < 4; i++)
            af[i]  = *(const short8*)&Ac[(wy * 64 + i * 16 + ln16) * LDK + ca];
#pragma unroll
        for (int j = 0; j < 2; j++)
            bf_[j] = *(const short8*)&Bc[(wx * 32 + j * 16 + ln16) * LDK + ca];
        if (t + 2 < nt) STAGE_GB(stg);
#pragma unroll
        for (int i = 0; i < 4; i++)
#pragma unroll
            for (int j = 0; j < 2; j++)
                acc[i][j] = __builtin_amdgcn_mfma_f32_16x16x32_bf16(af[i], bf_[j], acc[i][j], 0, 0, 0);
        cur = (cur == 2) ? 0 : cur + 1;
        stg = (stg == 2) ? 0 : stg + 1;
    }
#undef STAGE_GB

#pragma unroll
    for (int i = 0; i < 4; i++) {
#pragma unroll
        for (int j = 0; j < 2; j++) {
            const int col = bn + wx * 32 + j * 16 + ln16;
            const float b_ = bias ? bias[col] : 0.f;
#pragma unroll
            for (int r = 0; r < 4; r++) {
                const int row = bm + wy * 64 + i * 16 + qd * 4 + r;
                float v = acc[i][j][r] + b_;
                if (mode == 1) v = 0.5f * v * (1.0f + erff(v * 0.7071067811865476f));
                if (Cf)  Cf[(size_t)row * ldc + col] = v;
                if (Cb)  Cb[(size_t)row * ldcb + col] = f2bu(v);
                if (Cb2) Cb2[(size_t)row * ldcb2 + col] =
                             f2bu(aux[(size_t)row * ldaux + col] - v);
            }
        }
    }
}

// ---------------------------------------------------------------------------
// Dual-B fused gate GEMM: C = sigmoid(A@B1 + b1) * (A@B2 + b2), fp32 out.
// 128x64 tile, 3-buffer single-barrier pipeline, swizzled LDS.
// ---------------------------------------------------------------------------
__global__ __launch_bounds__(256) void gemm_bf2(
    const u16* __restrict__ A, int lda,
    const u16* __restrict__ B1t, const u16* __restrict__ B2t, int ldb,
    const float* __restrict__ bias1, const float* __restrict__ bias2,
    float* __restrict__ Cf, int ldc, int K)
{
    __shared__ u16 Asl[3][128 * LDK];
    __shared__ u16 B1sl[3][64 * LDK];
    __shared__ u16 B2sl[3][64 * LDK];
    const int tid = threadIdx.x;
    int bxs, bys;
    xcd_swz(bxs, bys);
    const int bm = bys * 128, bn = bxs * 64;
    const int lane = tid & 63, wave = tid >> 6;
    const int wy = wave >> 1, wx = wave & 1;
    const int qd = lane >> 4, ln16 = lane & 15;
    const int ca = (qd ^ ((ln16 >> 1) & 3)) * 8;

    const int srow = wave * 16 + (lane >> 2);
    const int scol = ((lane & 3) ^ ((lane >> 3) & 3)) * 8;
    const int lo   = wave * 16 * LDK;
    const size_t a64 = (size_t)64 * lda;
    const u16* pA  = A   + (size_t)bm * lda + (size_t)srow * lda + scol;
    const u16* pB1 = B1t + (size_t)bn * ldb + (size_t)srow * ldb + scol;
    const u16* pB2 = B2t + (size_t)bn * ldb + (size_t)srow * ldb + scol;

    f32x4 acc1[4][2], acc2[4][2];
#pragma unroll
    for (int i = 0; i < 4; i++)
#pragma unroll
        for (int j = 0; j < 2; j++)
#pragma unroll
            for (int r = 0; r < 4; r++) { acc1[i][j][r] = 0.f; acc2[i][j][r] = 0.f; }

#define STAGE_GB2(bi) do { \
    dma16(pA,       &Asl[bi][lo]); \
    dma16(pA + a64, &Asl[bi][lo + 64 * LDK]); \
    dma16(pB1,      &B1sl[bi][lo]); \
    dma16(pB2,      &B2sl[bi][lo]); \
    pA += 32; pB1 += 32; pB2 += 32; } while (0)

    const int nt = K >> 5;
    STAGE_GB2(0);
    STAGE_GB2(1);
    int cur = 0, stg = 2;
    for (int t = 0; t < nt; ++t) {
        if (t < nt - 1) { VMCNT(4); } else { VMCNT(0); }
        const u16* Ac  = Asl[cur];
        const u16* B1c = B1sl[cur];
        const u16* B2c = B2sl[cur];
        short8 af[4], b1f[2], b2f[2];
#pragma unroll
        for (int i = 0; i < 4; i++)
            af[i]  = *(const short8*)&Ac [(wy * 64 + i * 16 + ln16) * LDK + ca];
#pragma unroll
        for (int j = 0; j < 2; j++) {
            b1f[j] = *(const short8*)&B1c[(wx * 32 + j * 16 + ln16) * LDK + ca];
            b2f[j] = *(const short8*)&B2c[(wx * 32 + j * 16 + ln16) * LDK + ca];
        }
        if (t + 2 < nt) STAGE_GB2(stg);
#pragma unroll
        for (int i = 0; i < 4; i++)
#pragma unroll
            for (int j = 0; j < 2; j++) {
                acc1[i][j] = __builtin_amdgcn_mfma_f32_16x16x32_bf16(af[i], b1f[j], acc1[i][j], 0, 0, 0);
                acc2[i][j] = __builtin_amdgcn_mfma_f32_16x16x32_bf16(af[i], b2f[j], acc2[i][j], 0, 0, 0);
            }
        cur = (cur == 2) ? 0 : cur + 1;
        stg = (stg == 2) ? 0 : stg + 1;
    }
#undef STAGE_GB2

#pragma unroll
    for (int i = 0; i < 4; i++) {
#pragma unroll
        for (int j = 0; j < 2; j++) {
            const int col = bn + wx * 32 + j * 16 + ln16;
            const float b1_ = bias1[col], b2_ = bias2[col];
#pragma unroll
            for (int r = 0; r < 4; r++) {
                const int row = bm + wy * 64 + i * 16 + qd * 4 + r;
                const float g = 1.0f / (1.0f + expf(-(acc1[i][j][r] + b1_)));
                Cf[(size_t)row * ldc + col] = g * (acc2[i][j][r] + b2_);
            }
        }
    }
}

// ---------------------------------------------------------------------------
// LayerNorm over 512 features. in1b optional bf16 add. fp32 + optional bf16 out.
// ---------------------------------------------------------------------------
__global__ __launch_bounds__(256) void ln_kernel(
    const float* __restrict__ in0, int ld0,
    const u16* __restrict__ in1b, int ld1b,
    const float* __restrict__ g, const float* __restrict__ bta,
    float* __restrict__ outf, int ldo,
    u16* __restrict__ outb, int ldob)
{
    int row = blockIdx.x, tid = threadIdx.x;
    const float* p0 = in0 + (size_t)row * ld0;
    float v0 = p0[tid], v1 = p0[tid + 256];
    if (in1b) {
        const u16* p1 = in1b + (size_t)row * ld1b;
        union { unsigned u; float f; } c0, c1;
        c0.u = ((unsigned)p1[tid]) << 16;
        c1.u = ((unsigned)p1[tid + 256]) << 16;
        v0 += c0.f; v1 += c1.f;
    }
    float s = v0 + v1, sq = v0 * v0 + v1 * v1;
#pragma unroll
    for (int o = 32; o > 0; o >>= 1) {
        s  += __shfl_xor(s, o);
        sq += __shfl_xor(sq, o);
    }
    __shared__ float red[8];
    int wid = tid >> 6;
    if ((tid & 63) == 0) { red[wid] = s; red[4 + wid] = sq; }
    __syncthreads();
    s  = red[0] + red[1] + red[2] + red[3];
    sq = red[4] + red[5] + red[6] + red[7];
    float mean = s * (1.0f / 512.0f);
    float var  = sq * (1.0f / 512.0f) - mean * mean;
    float rstd = rsqrtf(var + 1e-5f);
    float o0 = (v0 - mean) * rstd * g[tid] + bta[tid];
    float o1 = (v1 - mean) * rstd * g[tid + 256] + bta[tid + 256];
    if (outf) {
        outf[(size_t)row * ldo + tid]       = o0;
        outf[(size_t)row * ldo + tid + 256] = o1;
    }
    if (outb) {
        outb[(size_t)row * ldob + tid]       = f2bu(o0);
        outb[(size_t)row * ldob + tid + 256] = f2bu(o1);
    }
}

// ---------------------------------------------------------------------------
// V^T precompute: vt[(bb*8+hh)][d=64][key=1024] = q[bb*1024+key][hh*64+d].
// LDS-tiled, coalesced both sides. Bit-exact copy.
// ---------------------------------------------------------------------------
__global__ __launch_bounds__(256) void trans_vt(const u16* __restrict__ q,
                                                u16* __restrict__ vt) {
    const int z  = blockIdx.z;            // bb*8+hh
    const int bb = z >> 3, hh = z & 7;
    const int k0 = blockIdx.x * 64;       // key tile
    const int d0 = blockIdx.y * 32;       // d tile
    __shared__ u16 t[64][33];
    const int tx = threadIdx.x & 31, ty = threadIdx.x >> 5;   // 32 x 8
    const u16* src = q + (size_t)(bb * SEQ + k0) * EDIM + hh * 64 + d0;
#pragma unroll
    for (int r = 0; r < 64; r += 8)
        t[ty + r][tx] = src[(size_t)(ty + r) * EDIM + tx];
    __syncthreads();
    const int ox = threadIdx.x & 63, oy = threadIdx.x >> 6;   // 64 x 4
    u16* dst = vt + ((size_t)z * 64 + d0) * SEQ + k0;
#pragma unroll
    for (int r = 0; r < 32; r += 4)
        dst[(size_t)(oy + r) * SEQ + ox] = t[ox][oy + r];
}

// ---------------------------------------------------------------------------
// MFMA flash attention, q==k==v bf16, head_dim 64. exp2-domain softmax.
// QBLK=128: two independent 64-row q-halves per block share each staged
// K/V^T tile, halving the per-CU DMA-drain count and K/V L2 re-reads.
// Single-buffer 24.5 KB LDS; XCD swizzle maps each XCD to one batch.
// Lane-local l accumulation; gated max reduce; Pw 16B-block XOR swizzle;
// s_setprio(1) around MFMA clusters. Bit-exact vs QBLK=64 version.
// Writes bf16 new_x into catb[:, 0:512] (ld 1024).
// ---------------------------------------------------------------------------
#define ANT 16  /* SEQ/64 k-tiles */

__global__ __launch_bounds__(256) void attn_mfma(const u16* __restrict__ qall,
                                                 const u16* __restrict__ vt,
                                                 u16* __restrict__ catb) {
    __shared__ u16 Ks[64 * 64];         // [key][d]  chunk-swizzled rows (8 KB)
    __shared__ u16 VTs[64 * 64];        // [d][key]  chunk-swizzled rows (8 KB)
    __shared__ u16 Pw[4][16 * 64];      // per-wave P, block-swizzled (8 KB)

    const int phys = blockIdx.x;        // 512 blocks
    const int bid = (phys & 7) * 64 + (phys >> 3);   // XCD-contiguous logical id
    const int lt = bid & 7, hh = (bid >> 3) & 7, bb = bid >> 6;
    const int q0 = lt * 128;
    const int tid = threadIdx.x;
    const int wave = tid >> 6, lane = tid & 63;
    const int quad = lane >> 4, ln16 = lane & 15;

    const u16* qh = qall + (size_t)bb * SEQ * EDIM + hh * 64;
    const u16* vh = vt + (size_t)(bb * 8 + hh) * 64 * SEQ;

    // Q fragments for both halves (rows q0+... and q0+64+...)
    const u16* qrowA = qh + (size_t)(q0 + wave * 16 + ln16) * EDIM + quad * 8;
    const short8 aqA0 = *(const short8*)(qrowA);
    const short8 aqA1 = *(const short8*)(qrowA + 32);
    const u16* qrowB = qrowA + (size_t)64 * EDIM;
    const short8 aqB0 = *(const short8*)(qrowB);
    const short8 aqB1 = *(const short8*)(qrowB + 32);

    f32x4 oaccA[4], oaccB[4];
    float m_runA = -1e30f, l_laneA = 0.f;
    float m_runB = -1e30f, l_laneB = 0.f;
#pragma unroll
    for (int j = 0; j < 4; j++)
#pragma unroll
        for (int r = 0; r < 4; r++) { oaccA[j][r] = 0.f; oaccB[j][r] = 0.f; }

    const int sw = ln16 & 7;             // row&7 for rows j*16+ln16
    const int c0 = (quad ^ sw) * 8;
    const int c1 = ((quad + 4) ^ sw) * 8;

    // hoisted staging geometry (chunk-XOR swizzle on global source)
    const int r0  = wave * 16 + (lane >> 3);
    const int r1  = r0 + 8;
    const int cg0 = (lane & 7) ^ (r0 & 7);
    const int cg1 = (lane & 7) ^ (r1 & 7);
    const u16* pK0 = qh + (size_t)r0 * EDIM + cg0 * 8;
    const u16* pK1 = qh + (size_t)r1 * EDIM + cg1 * 8;
    const u16* pV0 = vh + (size_t)r0 * SEQ + cg0 * 8;
    const u16* pV1 = vh + (size_t)r1 * SEQ + cg1 * 8;
    const int lds0 = (wave * 16) * 64;          // wave-uniform LDS bases
    const int lds1 = (wave * 16 + 8) * 64;

    for (int t = 0; t < ANT; ++t) {
        if (t) __syncthreads();          // all waves done reading prev tile
        dma16(pK0 + (size_t)t * 64 * EDIM, &Ks[lds0]);
        dma16(pK1 + (size_t)t * 64 * EDIM, &Ks[lds1]);
        dma16(pV0 + t * 64, &VTs[lds0]);
        dma16(pV1 + t * 64, &VTs[lds1]);
        __syncthreads();                 // drains DMA (vmcnt) + joins

        // preload V^T fragments once for both halves
        short8 vb0[4], vb1[4];
#pragma unroll
        for (int j = 0; j < 4; j++) {
            const int ro = (j * 16 + ln16) * 64;
            vb0[j] = *(const short8*)&VTs[ro + c0];
            vb1[j] = *(const short8*)&VTs[ro + c1];
        }

        // ======================= half A =======================
        {
            f32x4 S[4];
            __builtin_amdgcn_s_setprio(1);
#pragma unroll
            for (int j = 0; j < 4; j++) {
                const int ro = (j * 16 + ln16) * 64;
                short8 a0 = *(const short8*)&Ks[ro + c0];
                short8 a1 = *(const short8*)&Ks[ro + c1];
                f32x4 c = {0.f, 0.f, 0.f, 0.f};
                c = __builtin_amdgcn_mfma_f32_16x16x32_bf16(a0, aqA0, c, 0, 0, 0);
                c = __builtin_amdgcn_mfma_f32_16x16x32_bf16(a1, aqA1, c, 0, 0, 0);
                S[j] = c;
            }
            __builtin_amdgcn_s_setprio(0);

            float mxl = S[0][0];
#pragma unroll
            for (int j = 0; j < 4; j++)
#pragma unroll
                for (int r = 0; r < 4; r++) mxl = fmaxf(mxl, S[j][r]);
            const bool newm = __any(mxl > m_runA);
            float al = 1.0f;
            if (newm) {
                float mx = fmaxf(mxl, __shfl_xor(mxl, 16));
                mx = fmaxf(mx, __shfl_xor(mx, 32));
                const float mn = fmaxf(m_runA, mx);
                al = exp2f((m_runA - mn) * ATT_SCL);
                m_runA = mn;
            }
            const float ns = -m_runA * ATT_SCL;
            float p[4][4];
            float rsl = 0.f;
#pragma unroll
            for (int j = 0; j < 4; j++)
#pragma unroll
                for (int r = 0; r < 4; r++) {
                    p[j][r] = exp2f(fmaf(S[j][r], ATT_SCL, ns));
                    rsl += p[j][r];
                }
            l_laneA = l_laneA * al + rsl;
#pragma unroll
            for (int j = 0; j < 4; j++) {
                unsigned w0 = cvtpk_bf16(p[j][0], p[j][1]);
                unsigned w1 = cvtpk_bf16(p[j][2], p[j][3]);
                const int blk = (j * 2 + (quad >> 1)) ^ sw;
                *(uint2*)&Pw[wave][ln16 * 64 + blk * 8 + (quad & 1) * 4] =
                    make_uint2(w0, w1);
            }
            if (newm) {
                float alq[4];
#pragma unroll
                for (int r = 0; r < 4; r++) alq[r] = __shfl(al, quad * 4 + r);
#pragma unroll
                for (int j = 0; j < 4; j++)
#pragma unroll
                    for (int r = 0; r < 4; r++) oaccA[j][r] *= alq[r];
            }
            short8 pa0 = *(const short8*)&Pw[wave][ln16 * 64 + (quad ^ sw) * 8];
            short8 pa1 = *(const short8*)&Pw[wave][ln16 * 64 + ((quad + 4) ^ sw) * 8];
            __builtin_amdgcn_s_setprio(1);
#pragma unroll
            for (int j = 0; j < 4; j++) {
                oaccA[j] = __builtin_amdgcn_mfma_f32_16x16x32_bf16(pa0, vb0[j], oaccA[j], 0, 0, 0);
                oaccA[j] = __builtin_amdgcn_mfma_f32_16x16x32_bf16(pa1, vb1[j], oaccA[j], 0, 0, 0);
            }
            __builtin_amdgcn_s_setprio(0);
        }

        // ======================= half B =======================
        {
            f32x4 S[4];
            __builtin_amdgcn_s_setprio(1);
#pragma unroll
            for (int j = 0; j < 4; j++) {
                const int ro = (j * 16 + ln16) * 64;
                short8 a0 = *(const short8*)&Ks[ro + c0];
                short8 a1 = *(const short8*)&Ks[ro + c1];
                f32x4 c = {0.f, 0.f, 0.f, 0.f};
                c = __builtin_amdgcn_mfma_f32_16x16x32_bf16(a0, aqB0, c, 0, 0, 0);
                c = __builtin_amdgcn_mfma_f32_16x16x32_bf16(a1, aqB1, c, 0, 0, 0);
                S[j] = c;
            }
            __builtin_amdgcn_s_setprio(0);

            float mxl = S[0][0];
#pragma unroll
            for (int j = 0; j < 4; j++)
#pragma unroll
                for (int r = 0; r < 4; r++) mxl = fmaxf(mxl, S[j][r]);
            const bool newm = __any(mxl > m_runB);
            float al = 1.0f;
            if (newm) {
                float mx = fmaxf(mxl, __shfl_xor(mxl, 16));
                mx = fmaxf(mx, __shfl_xor(mx, 32));
                const float mn = fmaxf(m_runB, mx);
                al = exp2f((m_runB - mn) * ATT_SCL);
                m_runB = mn;
            }
            const float ns = -m_runB * ATT_SCL;
            float p[4][4];
            float rsl = 0.f;
#pragma unroll
            for (int j = 0; j < 4; j++)
#pragma unroll
                for (int r = 0; r < 4; r++) {
                    p[j][r] = exp2f(fmaf(S[j][r], ATT_SCL, ns));
                    rsl += p[j][r];
                }
            l_laneB = l_laneB * al + rsl;
#pragma unroll
            for (int j = 0; j < 4; j++) {
                unsigned w0 = cvtpk_bf16(p[j][0], p[j][1]);
                unsigned w1 = cvtpk_bf16(p[j][2], p[j][3]);
                const int blk = (j * 2 + (quad >> 1)) ^ sw;
                *(uint2*)&Pw[wave][ln16 * 64 + blk * 8 + (quad & 1) * 4] =
                    make_uint2(w0, w1);
            }
            if (newm) {
                float alq[4];
#pragma unroll
                for (int r = 0; r < 4; r++) alq[r] = __shfl(al, quad * 4 + r);
#pragma unroll
                for (int j = 0; j < 4; j++)
#pragma unroll
                    for (int r = 0; r < 4; r++) oaccB[j][r] *= alq[r];
            }
            short8 pa0 = *(const short8*)&Pw[wave][ln16 * 64 + (quad ^ sw) * 8];
            short8 pa1 = *(const short8*)&Pw[wave][ln16 * 64 + ((quad + 4) ^ sw) * 8];
            __builtin_amdgcn_s_setprio(1);
#pragma unroll
            for (int j = 0; j < 4; j++) {
                oaccB[j] = __builtin_amdgcn_mfma_f32_16x16x32_bf16(pa0, vb0[j], oaccB[j], 0, 0, 0);
                oaccB[j] = __builtin_amdgcn_mfma_f32_16x16x32_bf16(pa1, vb1[j], oaccB[j], 0, 0, 0);
            }
            __builtin_amdgcn_s_setprio(0);
        }
    }

    // final cross-quad denominator reductions (once per half)
    float lA = l_laneA;
    lA += __shfl_xor(lA, 16);
    lA += __shfl_xor(lA, 32);
    const float linvA = 1.0f / lA;
    float lB = l_laneB;
    lB += __shfl_xor(lB, 16);
    lB += __shfl_xor(lB, 32);
    const float linvB = 1.0f / lB;
    float invqA[4], invqB[4];
#pragma unroll
    for (int r = 0; r < 4; r++) {
        invqA[r] = __shfl(linvA, quad * 4 + r);
        invqB[r] = __shfl(linvB, quad * 4 + r);
    }
#pragma unroll
    for (int r = 0; r < 4; r++) {
        const int rowA = bb * SEQ + q0 + wave * 16 + quad * 4 + r;
#pragma unroll
        for (int j = 0; j < 4; j++) {
            const int col = hh * 64 + j * 16 + ln16;
            catb[(size_t)rowA * E2DIM + col] = f2bu(oaccA[j][r] * invqA[r]);
            catb[(size_t)(rowA + 64) * E2DIM + col] = f2bu(oaccB[j][r] * invqB[r]);
        }
    }
}

// ---------------------------------------------------------------------------
// Host launch
// ---------------------------------------------------------------------------
extern "C" void kernel_launch(void* const* d_in, const int* in_sizes, int n_in,
                              void* d_out, int out_size, void* d_ws, size_t ws_size,
                              hipStream_t stream)
{
    // ---- workspace layout (float units) ----
    const size_t OFF_MT0 = 0;
    const size_t OFF_MT1 = OFF_MT0 + 131072;
    const size_t OFF_MT2 = OFF_MT1 + 131072;
    const size_t OFF_MT3 = OFF_MT2 + 131072;
    const size_t OFF_MT4 = OFF_MT3 + 131072;
    const size_t OFF_MT5 = OFF_MT4 + 524288;
    const size_t OFF_XB  = OFF_MT5 + 524288;        // x_bf / x1_bf (bf16 8192x512)
    const size_t OFF_CB  = OFF_XB + 2097152;        // cat bf16 [8192,1024]
    const size_t OFF_BQ  = OFF_CB + 4194304;        // q bf16 -> x2 bf16
    const size_t OFF_BN  = OFF_BQ + 4194304;        // fold t1 scratch -> VT -> h fp32
    const size_t OFF_BC  = OFF_BN + 4194304;        // fold t2 scratch -> x1 fp32
    const size_t OFF_P   = OFF_BC + 4194304;        // fp32-converted inputs

    float* W = (float*)d_ws;
    u16* MT[6] = {(u16*)(W + OFF_MT0), (u16*)(W + OFF_MT1), (u16*)(W + OFF_MT2),
                  (u16*)(W + OFF_MT3), (u16*)(W + OFF_MT4), (u16*)(W + OFF_MT5)};
    u16*   XB  = (u16*)(W + OFF_XB);
    u16*   CB  = (u16*)(W + OFF_CB);
    u16*   QB  = (u16*)(W + OFF_BQ);   // q bf16; later x2 bf16 (sequential reuse)
    float* BN  = W + OFF_BN;           // VT (during attn) -> h fp32 (after)
    float* BC  = W + OFF_BC;           // x1 fp32 (after fold)
    u16*   VT  = (u16*)BN;             // V^T bf16 [64][64][1024] (8 MB of 16 MB)

    float* F[23];
    CvtBatch cb;
    int pre = 0;
    for (int i = 0; i < 23 && i < n_in; i++) {
        cb.pre4[i] = pre;
        F[i] = W + OFF_P + (size_t)pre * 4;
        cb.src[i] = d_in[i];
        cb.dst[i] = (float4*)F[i];
        pre += in_sizes[i] / 4;
    }
    cb.pre4[23] = pre;
    const int total4 = pre;
    int* FLAG = (int*)(W + OFF_P + (size_t)total4 * 4);

    if (n_in < 23) return;
    if (ws_size < (OFF_P + (size_t)total4 * 4 + 16) * sizeof(float)) return;

    detect_dtype<<<1, 256, 0, stream>>>((const u16*)d_in[0], FLAG);
    cvt_all<<<(total4 + 255) / 256, 256, 0, stream>>>(cb, total4, FLAG);
    f2b_kernel<<<(ROWS * EDIM / 4 + 255) / 256, 256, 0, stream>>>(F[0], XB, ROWS * EDIM / 4);

    // ---- fold (3 batched launches): scratch overlays BN/BC (dead here) ----
    FoldBatch fb;
    {
        const int wi[6] = {1, 4, 7, 10, 13, 16};
        u16* T1 = (u16*)BN;
        u16* T2 = (u16*)BC;
        size_t off = 0;
        for (int s = 0; s < 6; s++) {
            const int n = (s < 4) ? 512 : 1024;
            fb.w[s]  = F[wi[s]];
            fb.fw[s] = F[wi[s] + 1];
            fb.t1[s] = T1 + off;
            fb.t2[s] = T2 + off;
            fb.mt[s] = MT[s];
            fb.n[s]  = n;
            fb.lg[s] = (s < 4) ? 9 : 10;
            fb.sc[s] = (s < 4) ? 0.04419417382415922f : 0.03125f;
            off += (size_t)n * n;
        }
    }
    fold_trconv<<<dim3(32, 32, 6), 256, 0, stream>>>(fb);
    fold_circ<<<dim3(4096, 1, 6), 256, 0, stream>>>(fb);
    fold_gemm<<<dim3(8, 8, 6), 256, 0, stream>>>(fb);

    float* out0 = (float*)d_out;                       // LN(h): [8192,512]
    float* out1 = (float*)d_out + (size_t)ROWS * EDIM; // out:   [8192,1024]

    // q = x @ M0 + attn_fb                                  -> QB (bf16)
    gemm_bf<<<dim3(8, 64), 256, 0, stream>>>(
        XB, 512, MT[0], 512, F[3], nullptr, 0, QB, 512, nullptr, 0, nullptr, 0, 512, 0);
    // V^T precompute (QB -> VT in BN region, dead until gemm_bf2 writes h)
    trans_vt<<<dim3(16, 2, 64), 256, 0, stream>>>(QB, VT);
    // attention -> cat bf16 [:, :512]  (512 blocks, 2 q-tiles each)
    attn_mfma<<<512, 256, 0, stream>>>(QB, VT, CB);
    // x1 = LN(x + newx; n1)                                 -> BC fp32 + XB bf16
    ln_kernel<<<8192, 256, 0, stream>>>(F[0], 512, CB, 1024, F[19], F[20],
                                        BC, 512, XB, 512);
    // x_ln = gelu(x1 @ M1 + b); cat[:,512:]=bf16(v); x2=bf16(x1-v) -> QB
    gemm_bf<<<dim3(8, 64), 256, 0, stream>>>(
        XB, 512, MT[1], 512, F[6], nullptr, 0, CB + 512, 1024, QB, 512, BC, 512, 512, 1);
    // h = sigmoid(x2@M2+b2) * (x2@M3+b3)                     -> BN fp32
    gemm_bf2<<<dim3(8, 64), 256, 0, stream>>>(
        QB, 512, MT[2], MT[3], 512, F[9], F[12], BN, 512, 512);
    // out0 = LN(h; n2)                                       -> d_out
    ln_kernel<<<8192, 256, 0, stream>>>(BN, 512, nullptr, 0, F[21], F[22],
                                        out0, 512, nullptr, 0);
    // out1 = sigmoid(cat@M4+b4) * (cat@M5+b5)                -> d_out+4M
    gemm_bf2<<<dim3(16, 64), 256, 0, stream>>>(
        CB, 1024, MT[4], MT[5], 1024, F[15], F[18], out1, 1024, 1024);
}

// Round 16
// 325.754 us; speedup vs baseline: 1.0159x; 1.0159x over previous
//
#include <hip/hip_runtime.h>
#include <hip/hip_bf16.h>
#include <math.h>

typedef __hip_bfloat16 bf16;
typedef unsigned short u16;
typedef __attribute__((ext_vector_type(8))) short short8;
typedef __attribute__((ext_vector_type(4))) float f32x4;

#define NB      8
#define SEQ     1024
#define EDIM    512
#define E2DIM   1024
#define ROWS    8192
#define INV_SQRT_E 0.04419417382415922f
#define ATT_SCL    0.06375985678148161f   /* INV_SQRT_E * log2(e) */

__device__ inline u16 f2bu(float f) {           // fp32 -> bf16 bits, RNE
    union { float f; unsigned u; } c; c.f = f;
    return (u16)((c.u + 0x7FFF + ((c.u >> 16) & 1)) >> 16);
}

__device__ __forceinline__ unsigned cvtpk_bf16(float lo, float hi) {
    unsigned r;
    asm("v_cvt_pk_bf16_f32 %0, %1, %2" : "=v"(r) : "v"(lo), "v"(hi));
    return r;
}

// counted-vmcnt pipeline fence (T4): loads stay in flight across barriers.
#define VMCNT(N) do { \
    asm volatile("s_waitcnt vmcnt(" #N ")" ::: "memory"); \
    __builtin_amdgcn_sched_barrier(0); \
    __builtin_amdgcn_s_barrier(); \
    __builtin_amdgcn_sched_barrier(0); } while (0)

__device__ __forceinline__ void dma16(const u16* g, u16* l) {
    __builtin_amdgcn_global_load_lds(
        (const __attribute__((address_space(1))) void*)g,
        (__attribute__((address_space(3))) void*)l, 16, 0, 0);
}

// ---------------------------------------------------------------------------
// Input dtype autodetect (proved inputs are fp32; kept as cheap insurance).
// ---------------------------------------------------------------------------
__global__ __launch_bounds__(256) void detect_dtype(const u16* __restrict__ x,
                                                    int* __restrict__ flag) {
    int t = threadIdx.x;
    int cnt = 0;
    for (int k = t; k < 8192; k += 256) {
        int e = (x[k] >> 7) & 0xFF;
        if (e >= 0xC0) cnt++;
    }
#pragma unroll
    for (int o = 32; o > 0; o >>= 1) cnt += __shfl_xor(cnt, o);
    __shared__ int red[4];
    if ((t & 63) == 0) red[t >> 6] = cnt;
    __syncthreads();
    if (t == 0) flag[0] = (red[0] + red[1] + red[2] + red[3] > 100) ? 1 : 0;
}

// ---------------------------------------------------------------------------
// Batch conversion of all 23 inputs -> fp32 workspace (dtype-adaptive).
// ---------------------------------------------------------------------------
struct CvtBatch {
    const void* src[23];
    float4*     dst[23];
    int         pre4[24];
};

__global__ __launch_bounds__(256) void cvt_all(CvtBatch a, int total4,
                                               const int* __restrict__ flag) {
    int t = blockIdx.x * 256 + threadIdx.x;
    if (t >= total4) return;
    int lo = 0;
    while (t >= a.pre4[lo + 1]) lo++;
    int li = t - a.pre4[lo];
    if (flag[0]) {
        a.dst[lo][li] = ((const float4*)a.src[lo])[li];
    } else {
        ushort4 u = ((const ushort4*)a.src[lo])[li];
        union { unsigned int i; float f; } c;
        float4 o;
        c.i = ((unsigned)u.x) << 16; o.x = c.f;
        c.i = ((unsigned)u.y) << 16; o.y = c.f;
        c.i = ((unsigned)u.z) << 16; o.z = c.f;
        c.i = ((unsigned)u.w) << 16; o.w = c.f;
        a.dst[lo][li] = o;
    }
}

// fp32 -> bf16 elementwise, n/4 threads
__global__ __launch_bounds__(256) void f2b_kernel(const float* __restrict__ src,
                                                  u16* __restrict__ dst, int n4) {
    int i = blockIdx.x * 256 + threadIdx.x;
    if (i >= n4) return;
    float4 a = ((const float4*)src)[i];
    ushort4 o;
    o.x = f2bu(a.x); o.y = f2bu(a.y); o.z = f2bu(a.z); o.w = f2bu(a.w);
    ((ushort4*)dst)[i] = o;
}

#define LDK 32   /* linear LDS row: 32 bf16 = 64 B = 4 chunks of 16 B */

// Bijective XCD-aware block swizzle (requires gridDim.x*gridDim.y % 8 == 0).
__device__ __forceinline__ void xcd_swz(int& bx, int& by) {
    const int nx  = gridDim.x;
    const int nwg = nx * gridDim.y;
    const int lid = blockIdx.y * nx + blockIdx.x;
    const int q   = nwg >> 3;
    const int s   = (lid & 7) * q + (lid >> 3);
    bx = s % nx;
    by = s / nx;
}

// ---------------------------------------------------------------------------
// Fold batch: 6 spectral layers, z-indexed kernels (3 launches total).
// ---------------------------------------------------------------------------
struct FoldBatch {
    const float* w[6];
    const float* fw[6];
    u16* t1[6];
    u16* t2[6];
    u16* mt[6];
    int  n[6], lg[6];
    float sc[6];
};

__global__ __launch_bounds__(256) void fold_trconv(FoldBatch fb) {
    const int z = blockIdx.z;
    const int n = fb.n[z];
    const int bx = blockIdx.x * 32, by = blockIdx.y * 32;
    if (bx >= n || by >= n) return;
    __shared__ float t[32][33];
    const int tx = threadIdx.x & 31, ty = threadIdx.x >> 5;   // 32x8
    const float* src = fb.fw[z];
    u16* dst = fb.t1[z];
#pragma unroll
    for (int r = 0; r < 32; r += 8)
        t[ty + r][tx] = src[(size_t)(by + ty + r) * n + bx + tx];
    __syncthreads();
#pragma unroll
    for (int r = 0; r < 32; r += 8)
        dst[(size_t)(bx + ty + r) * n + by + tx] = f2bu(t[tx][ty + r]);
}

__global__ __launch_bounds__(256) void fold_circ(FoldBatch fb) {
    const int z = blockIdx.z;
    const int n = fb.n[z], lg = fb.lg[z];
    int idx = blockIdx.x * 256 + threadIdx.x;
    if (idx >= n * n) return;
    int mask = n - 1;
    int m = idx & mask;
    int j = idx >> lg;
    fb.t2[z][idx] = f2bu(fb.w[z][(m - j) & mask]);
}

// 3-buffer single-barrier pipeline, hoisted staging addresses.
__global__ __launch_bounds__(256) void fold_gemm(FoldBatch fb) {
    const int z = blockIdx.z;
    const int n = fb.n[z];
    const int bm = blockIdx.y * 128, bn = blockIdx.x * 128;
    if (bm >= n || bn >= n) return;
    const u16* A  = fb.t1[z];
    const u16* Bt = fb.t2[z];
    u16* Mt = fb.mt[z];
    const float scale = fb.sc[z];

    __shared__ u16 Asl[3][128 * LDK];
    __shared__ u16 Bsl[3][128 * LDK];
    const int tid = threadIdx.x;
    const int lane = tid & 63, wave = tid >> 6;
    const int wy = wave >> 1, wx = wave & 1;
    const int qd = lane >> 4, ln16 = lane & 15;
    const int ca = (qd ^ ((ln16 >> 1) & 3)) * 8;   // swizzled read chunk

    const int srow = wave * 16 + (lane >> 2);
    const int scol = ((lane & 3) ^ ((lane >> 3) & 3)) * 8;
    const int lo   = wave * 16 * LDK;
    const size_t a64 = (size_t)64 * n;
    const u16* pA = A  + (size_t)bm * n + (size_t)srow * n + scol;
    const u16* pB = Bt + (size_t)bn * n + (size_t)srow * n + scol;

    f32x4 acc[4][4];
#pragma unroll
    for (int i = 0; i < 4; i++)
#pragma unroll
        for (int j = 0; j < 4; j++)
#pragma unroll
            for (int r = 0; r < 4; r++) acc[i][j][r] = 0.f;

#define STAGE_FG(bi) do { \
    dma16(pA,       &Asl[bi][lo]); \
    dma16(pA + a64, &Asl[bi][lo + 64 * LDK]); \
    dma16(pB,       &Bsl[bi][lo]); \
    dma16(pB + a64, &Bsl[bi][lo + 64 * LDK]); \
    pA += 32; pB += 32; } while (0)

    const int nt = n >> 5;
    STAGE_FG(0);
    STAGE_FG(1);
    int cur = 0, stg = 2;
    for (int t = 0; t < nt; ++t) {
        if (t < nt - 1) { VMCNT(4); } else { VMCNT(0); }
        const u16* Ac = Asl[cur];
        const u16* Bc = Bsl[cur];
        short8 af[4], bf_[4];
#pragma unroll
        for (int i = 0; i < 4; i++) {
            af[i]  = *(const short8*)&Ac[(wy * 64 + i * 16 + ln16) * LDK + ca];
            bf_[i] = *(const short8*)&Bc[(wx * 64 + i * 16 + ln16) * LDK + ca];
        }
        if (t + 2 < nt) STAGE_FG(stg);
#pragma unroll
        for (int i = 0; i < 4; i++)
#pragma unroll
            for (int j = 0; j < 4; j++)
                acc[i][j] = __builtin_amdgcn_mfma_f32_16x16x32_bf16(af[i], bf_[j], acc[i][j], 0, 0, 0);
        cur = (cur == 2) ? 0 : cur + 1;
        stg = (stg == 2) ? 0 : stg + 1;
    }
#undef STAGE_FG
#pragma unroll
    for (int i = 0; i < 4; i++)
#pragma unroll
        for (int j = 0; j < 4; j++) {
            const int col = bn + wx * 64 + j * 16 + ln16;
#pragma unroll
            for (int r = 0; r < 4; r++) {
                const int row = bm + wy * 64 + i * 16 + qd * 4 + r;
                Mt[(size_t)row * n + col] = f2bu(acc[i][j][r] * scale);
            }
        }
}

// ---------------------------------------------------------------------------
// bf16 MFMA GEMM (single B): C = act( A @ B + bias ). B pre-transposed.
// 128x64 tile, BK=32, 3-buffer single-barrier pipeline, swizzled LDS.
// ---------------------------------------------------------------------------
__global__ __launch_bounds__(256) void gemm_bf(
    const u16* __restrict__ A, int lda,
    const u16* __restrict__ Bt, int ldb,
    const float* __restrict__ bias,
    float* __restrict__ Cf, int ldc,
    u16* __restrict__ Cb, int ldcb,
    u16* __restrict__ Cb2, int ldcb2,
    const float* __restrict__ aux, int ldaux,
    int K, int mode)
{
    __shared__ u16 Asl[3][128 * LDK];
    __shared__ u16 Bsl[3][64 * LDK];
    const int tid = threadIdx.x;
    int bxs, bys;
    xcd_swz(bxs, bys);
    const int bm = bys * 128, bn = bxs * 64;
    const int lane = tid & 63, wave = tid >> 6;
    const int wy = wave >> 1, wx = wave & 1;
    const int qd = lane >> 4, ln16 = lane & 15;
    const int ca = (qd ^ ((ln16 >> 1) & 3)) * 8;

    const int srow = wave * 16 + (lane >> 2);
    const int scol = ((lane & 3) ^ ((lane >> 3) & 3)) * 8;
    const int lo   = wave * 16 * LDK;
    const size_t a64 = (size_t)64 * lda;
    const u16* pA = A  + (size_t)bm * lda + (size_t)srow * lda + scol;
    const u16* pB = Bt + (size_t)bn * ldb + (size_t)srow * ldb + scol;

    f32x4 acc[4][2];
#pragma unroll
    for (int i = 0; i < 4; i++)
#pragma unroll
        for (int j = 0; j < 2; j++)
#pragma unroll
            for (int r = 0; r < 4; r++) acc[i][j][r] = 0.f;

#define STAGE_GB(bi) do { \
    dma16(pA,       &Asl[bi][lo]); \
    dma16(pA + a64, &Asl[bi][lo + 64 * LDK]); \
    dma16(pB,       &Bsl[bi][lo]); \
    pA += 32; pB += 32; } while (0)

    const int nt = K >> 5;
    STAGE_GB(0);
    STAGE_GB(1);
    int cur = 0, stg = 2;
    for (int t = 0; t < nt; ++t) {
        if (t < nt - 1) { VMCNT(3); } else { VMCNT(0); }
        const u16* Ac = Asl[cur];
        const u16* Bc = Bsl[cur];
        short8 af[4], bf_[2];
#pragma unroll
        for (int i = 0; i < 4; i++)
            af[i]  = *(const short8*)&Ac[(wy * 64 + i * 16 + ln16) * LDK + ca];
#pragma unroll
        for (int j = 0; j < 2; j++)
            bf_[j] = *(const short8*)&Bc[(wx * 32 + j * 16 + ln16) * LDK + ca];
        if (t + 2 < nt) STAGE_GB(stg);
#pragma unroll
        for (int i = 0; i < 4; i++)
#pragma unroll
            for (int j = 0; j < 2; j++)
                acc[i][j] = __builtin_amdgcn_mfma_f32_16x16x32_bf16(af[i], bf_[j], acc[i][j], 0, 0, 0);
        cur = (cur == 2) ? 0 : cur + 1;
        stg = (stg == 2) ? 0 : stg + 1;
    }
#undef STAGE_GB

#pragma unroll
    for (int i = 0; i < 4; i++) {
#pragma unroll
        for (int j = 0; j < 2; j++) {
            const int col = bn + wx * 32 + j * 16 + ln16;
            const float b_ = bias ? bias[col] : 0.f;
#pragma unroll
            for (int r = 0; r < 4; r++) {
                const int row = bm + wy * 64 + i * 16 + qd * 4 + r;
                float v = acc[i][j][r] + b_;
                if (mode == 1) v = 0.5f * v * (1.0f + erff(v * 0.7071067811865476f));
                if (Cf)  Cf[(size_t)row * ldc + col] = v;
                if (Cb)  Cb[(size_t)row * ldcb + col] = f2bu(v);
                if (Cb2) Cb2[(size_t)row * ldcb2 + col] =
                             f2bu(aux[(size_t)row * ldaux + col] - v);
            }
        }
    }
}

// ---------------------------------------------------------------------------
// Dual-B fused gate GEMM: C = sigmoid(A@B1 + b1) * (A@B2 + b2), fp32 out.
// 128x64 tile, 3-buffer single-barrier pipeline, swizzled LDS.
// ---------------------------------------------------------------------------
__global__ __launch_bounds__(256) void gemm_bf2(
    const u16* __restrict__ A, int lda,
    const u16* __restrict__ B1t, const u16* __restrict__ B2t, int ldb,
    const float* __restrict__ bias1, const float* __restrict__ bias2,
    float* __restrict__ Cf, int ldc, int K)
{
    __shared__ u16 Asl[3][128 * LDK];
    __shared__ u16 B1sl[3][64 * LDK];
    __shared__ u16 B2sl[3][64 * LDK];
    const int tid = threadIdx.x;
    int bxs, bys;
    xcd_swz(bxs, bys);
    const int bm = bys * 128, bn = bxs * 64;
    const int lane = tid & 63, wave = tid >> 6;
    const int wy = wave >> 1, wx = wave & 1;
    const int qd = lane >> 4, ln16 = lane & 15;
    const int ca = (qd ^ ((ln16 >> 1) & 3)) * 8;

    const int srow = wave * 16 + (lane >> 2);
    const int scol = ((lane & 3) ^ ((lane >> 3) & 3)) * 8;
    const int lo   = wave * 16 * LDK;
    const size_t a64 = (size_t)64 * lda;
    const u16* pA  = A   + (size_t)bm * lda + (size_t)srow * lda + scol;
    const u16* pB1 = B1t + (size_t)bn * ldb + (size_t)srow * ldb + scol;
    const u16* pB2 = B2t + (size_t)bn * ldb + (size_t)srow * ldb + scol;

    f32x4 acc1[4][2], acc2[4][2];
#pragma unroll
    for (int i = 0; i < 4; i++)
#pragma unroll
        for (int j = 0; j < 2; j++)
#pragma unroll
            for (int r = 0; r < 4; r++) { acc1[i][j][r] = 0.f; acc2[i][j][r] = 0.f; }

#define STAGE_GB2(bi) do { \
    dma16(pA,       &Asl[bi][lo]); \
    dma16(pA + a64, &Asl[bi][lo + 64 * LDK]); \
    dma16(pB1,      &B1sl[bi][lo]); \
    dma16(pB2,      &B2sl[bi][lo]); \
    pA += 32; pB1 += 32; pB2 += 32; } while (0)

    const int nt = K >> 5;
    STAGE_GB2(0);
    STAGE_GB2(1);
    int cur = 0, stg = 2;
    for (int t = 0; t < nt; ++t) {
        if (t < nt - 1) { VMCNT(4); } else { VMCNT(0); }
        const u16* Ac  = Asl[cur];
        const u16* B1c = B1sl[cur];
        const u16* B2c = B2sl[cur];
        short8 af[4], b1f[2], b2f[2];
#pragma unroll
        for (int i = 0; i < 4; i++)
            af[i]  = *(const short8*)&Ac [(wy * 64 + i * 16 + ln16) * LDK + ca];
#pragma unroll
        for (int j = 0; j < 2; j++) {
            b1f[j] = *(const short8*)&B1c[(wx * 32 + j * 16 + ln16) * LDK + ca];
            b2f[j] = *(const short8*)&B2c[(wx * 32 + j * 16 + ln16) * LDK + ca];
        }
        if (t + 2 < nt) STAGE_GB2(stg);
#pragma unroll
        for (int i = 0; i < 4; i++)
#pragma unroll
            for (int j = 0; j < 2; j++) {
                acc1[i][j] = __builtin_amdgcn_mfma_f32_16x16x32_bf16(af[i], b1f[j], acc1[i][j], 0, 0, 0);
                acc2[i][j] = __builtin_amdgcn_mfma_f32_16x16x32_bf16(af[i], b2f[j], acc2[i][j], 0, 0, 0);
            }
        cur = (cur == 2) ? 0 : cur + 1;
        stg = (stg == 2) ? 0 : stg + 1;
    }
#undef STAGE_GB2

#pragma unroll
    for (int i = 0; i < 4; i++) {
#pragma unroll
        for (int j = 0; j < 2; j++) {
            const int col = bn + wx * 32 + j * 16 + ln16;
            const float b1_ = bias1[col], b2_ = bias2[col];
#pragma unroll
            for (int r = 0; r < 4; r++) {
                const int row = bm + wy * 64 + i * 16 + qd * 4 + r;
                const float g = 1.0f / (1.0f + expf(-(acc1[i][j][r] + b1_)));
                Cf[(size_t)row * ldc + col] = g * (acc2[i][j][r] + b2_);
            }
        }
    }
}

// ---------------------------------------------------------------------------
// LayerNorm over 512 features. in1b optional bf16 add. fp32 + optional bf16 out.
// ---------------------------------------------------------------------------
__global__ __launch_bounds__(256) void ln_kernel(
    const float* __restrict__ in0, int ld0,
    const u16* __restrict__ in1b, int ld1b,
    const float* __restrict__ g, const float* __restrict__ bta,
    float* __restrict__ outf, int ldo,
    u16* __restrict__ outb, int ldob)
{
    int row = blockIdx.x, tid = threadIdx.x;
    const float* p0 = in0 + (size_t)row * ld0;
    float v0 = p0[tid], v1 = p0[tid + 256];
    if (in1b) {
        const u16* p1 = in1b + (size_t)row * ld1b;
        union { unsigned u; float f; } c0, c1;
        c0.u = ((unsigned)p1[tid]) << 16;
        c1.u = ((unsigned)p1[tid + 256]) << 16;
        v0 += c0.f; v1 += c1.f;
    }
    float s = v0 + v1, sq = v0 * v0 + v1 * v1;
#pragma unroll
    for (int o = 32; o > 0; o >>= 1) {
        s  += __shfl_xor(s, o);
        sq += __shfl_xor(sq, o);
    }
    __shared__ float red[8];
    int wid = tid >> 6;
    if ((tid & 63) == 0) { red[wid] = s; red[4 + wid] = sq; }
    __syncthreads();
    s  = red[0] + red[1] + red[2] + red[3];
    sq = red[4] + red[5] + red[6] + red[7];
    float mean = s * (1.0f / 512.0f);
    float var  = sq * (1.0f / 512.0f) - mean * mean;
    float rstd = rsqrtf(var + 1e-5f);
    float o0 = (v0 - mean) * rstd * g[tid] + bta[tid];
    float o1 = (v1 - mean) * rstd * g[tid + 256] + bta[tid + 256];
    if (outf) {
        outf[(size_t)row * ldo + tid]       = o0;
        outf[(size_t)row * ldo + tid + 256] = o1;
    }
    if (outb) {
        outb[(size_t)row * ldob + tid]       = f2bu(o0);
        outb[(size_t)row * ldob + tid + 256] = f2bu(o1);
    }
}

// ---------------------------------------------------------------------------
// V^T precompute: vt[(bb*8+hh)][d=64][key=1024] = q[bb*1024+key][hh*64+d].
// LDS-tiled, coalesced both sides. Bit-exact copy.
// ---------------------------------------------------------------------------
__global__ __launch_bounds__(256) void trans_vt(const u16* __restrict__ q,
                                                u16* __restrict__ vt) {
    const int z  = blockIdx.z;            // bb*8+hh
    const int bb = z >> 3, hh = z & 7;
    const int k0 = blockIdx.x * 64;       // key tile
    const int d0 = blockIdx.y * 32;       // d tile
    __shared__ u16 t[64][33];
    const int tx = threadIdx.x & 31, ty = threadIdx.x >> 5;   // 32 x 8
    const u16* src = q + (size_t)(bb * SEQ + k0) * EDIM + hh * 64 + d0;
#pragma unroll
    for (int r = 0; r < 64; r += 8)
        t[ty + r][tx] = src[(size_t)(ty + r) * EDIM + tx];
    __syncthreads();
    const int ox = threadIdx.x & 63, oy = threadIdx.x >> 6;   // 64 x 4
    u16* dst = vt + ((size_t)z * 64 + d0) * SEQ + k0;
#pragma unroll
    for (int r = 0; r < 32; r += 4)
        dst[(size_t)(oy + r) * SEQ + ox] = t[ox][oy + r];
}

// ---------------------------------------------------------------------------
// MFMA flash attention, q==k==v bf16, head_dim 64. exp2-domain softmax.
// S^T orientation; K and precomputed V^T staged via swizzled global_load_lds.
// Single-buffer (24.5 KB LDS -> 4 blocks/CU), XCD-swizzled block ids.
// Lane-local l accumulation; gated max reduction (bit-exact skips).
// Pw at AP=64 with 16B-block XOR swizzle (bank-conflict-free).
// s_setprio(1) around MFMA clusters (T5: cross-block arbitration).
// Writes bf16 new_x into catb[:, 0:512] (ld 1024).
// ---------------------------------------------------------------------------
#define ANT 16  /* SEQ/64 k-tiles */

__global__ __launch_bounds__(256) void attn_mfma(const u16* __restrict__ qall,
                                                 const u16* __restrict__ vt,
                                                 u16* __restrict__ catb) {
    __shared__ u16 Ks[64 * 64];         // [key][d]  chunk-swizzled rows (8 KB)
    __shared__ u16 VTs[64 * 64];        // [d][key]  chunk-swizzled rows (8 KB)
    __shared__ u16 Pw[4][16 * 64];      // per-wave P, block-swizzled (8 KB)

    const int phys = blockIdx.x;
    const int bid = (phys & 7) * 128 + (phys >> 3);  // XCD-contiguous logical id
    const int lt = bid & 15, hh = (bid >> 4) & 7, bb = bid >> 7;
    const int q0 = lt * 64;
    const int tid = threadIdx.x;
    const int wave = tid >> 6, lane = tid & 63;
    const int quad = lane >> 4, ln16 = lane & 15;

    const u16* qh = qall + (size_t)bb * SEQ * EDIM + hh * 64;
    const u16* vh = vt + (size_t)(bb * 8 + hh) * 64 * SEQ;

    const u16* qrow = qh + (size_t)(q0 + wave * 16 + ln16) * EDIM + quad * 8;
    const short8 aq0 = *(const short8*)(qrow);
    const short8 aq1 = *(const short8*)(qrow + 32);

    f32x4 oacc[4];
    float m_run = -1e30f;                // running max for q = ln16 (uniform/quad)
    float l_lane = 0.f;                  // lane-local partial denominator
#pragma unroll
    for (int j = 0; j < 4; j++)
#pragma unroll
        for (int r = 0; r < 4; r++) oacc[j][r] = 0.f;

    const int sw = ln16 & 7;             // row&7 for rows j*16+ln16
    const int c0 = (quad ^ sw) * 8;
    const int c1 = ((quad + 4) ^ sw) * 8;

    // hoisted staging geometry (chunk-XOR swizzle on global source)
    const int r0  = wave * 16 + (lane >> 3);
    const int r1  = r0 + 8;
    const int cg0 = (lane & 7) ^ (r0 & 7);
    const int cg1 = (lane & 7) ^ (r1 & 7);
    const u16* pK0 = qh + (size_t)r0 * EDIM + cg0 * 8;
    const u16* pK1 = qh + (size_t)r1 * EDIM + cg1 * 8;
    const u16* pV0 = vh + (size_t)r0 * SEQ + cg0 * 8;
    const u16* pV1 = vh + (size_t)r1 * SEQ + cg1 * 8;
    const int lds0 = (wave * 16) * 64;          // wave-uniform LDS bases
    const int lds1 = (wave * 16 + 8) * 64;

    for (int t = 0; t < ANT; ++t) {
        if (t) __syncthreads();          // all waves done reading prev tile
        dma16(pK0 + (size_t)t * 64 * EDIM, &Ks[lds0]);
        dma16(pK1 + (size_t)t * 64 * EDIM, &Ks[lds1]);
        dma16(pV0 + t * 64, &VTs[lds0]);
        dma16(pV1 + t * 64, &VTs[lds1]);
        __syncthreads();                 // drains DMA (vmcnt) + joins

        // QK^T: S^T[j] lane(quad,ln16) reg r = scores[key=j*16+quad*4+r][q=ln16]
        f32x4 S[4];
        __builtin_amdgcn_s_setprio(1);
#pragma unroll
        for (int j = 0; j < 4; j++) {
            const int ro = (j * 16 + ln16) * 64;
            short8 a0 = *(const short8*)&Ks[ro + c0];
            short8 a1 = *(const short8*)&Ks[ro + c1];
            f32x4 c = {0.f, 0.f, 0.f, 0.f};
            c = __builtin_amdgcn_mfma_f32_16x16x32_bf16(a0, aq0, c, 0, 0, 0);
            c = __builtin_amdgcn_mfma_f32_16x16x32_bf16(a1, aq1, c, 0, 0, 0);
            S[j] = c;
        }
        __builtin_amdgcn_s_setprio(0);

        // local max over this lane's 16 keys
        float mxl = S[0][0];
#pragma unroll
        for (int j = 0; j < 4; j++)
#pragma unroll
            for (int r = 0; r < 4; r++) mxl = fmaxf(mxl, S[j][r]);

        // gated cross-quad max reduce (wave-uniform decision; bit-exact skip)
        const bool newm = __any(mxl > m_run);
        float al = 1.0f;
        if (newm) {
            float mx = fmaxf(mxl, __shfl_xor(mxl, 16));
            mx = fmaxf(mx, __shfl_xor(mx, 32));
            const float mn = fmaxf(m_run, mx);
            al = exp2f((m_run - mn) * ATT_SCL);
            m_run = mn;
        }
        const float ns = -m_run * ATT_SCL;
        float p[4][4];
        float rsl = 0.f;
#pragma unroll
        for (int j = 0; j < 4; j++)
#pragma unroll
            for (int r = 0; r < 4; r++) {
                p[j][r] = exp2f(fmaf(S[j][r], ATT_SCL, ns));
                rsl += p[j][r];
            }
        l_lane = l_lane * al + rsl;      // lane-local; cross-quad sum at end

        // pack P -> Pw[wave], row q=ln16, 16B-block b stored at b^sw.
        // key j*16+quad*4 -> block j*2+(quad>>1), 8B-half quad&1.
#pragma unroll
        for (int j = 0; j < 4; j++) {
            unsigned w0 = cvtpk_bf16(p[j][0], p[j][1]);
            unsigned w1 = cvtpk_bf16(p[j][2], p[j][3]);
            const int blk = (j * 2 + (quad >> 1)) ^ sw;
            *(uint2*)&Pw[wave][ln16 * 64 + blk * 8 + (quad & 1) * 4] =
                make_uint2(w0, w1);
        }

        // rescale O only when a new max appeared (bit-exact skip otherwise)
        if (newm) {
            float alq[4];
#pragma unroll
            for (int r = 0; r < 4; r++) alq[r] = __shfl(al, quad * 4 + r);
#pragma unroll
            for (int j = 0; j < 4; j++)
#pragma unroll
                for (int r = 0; r < 4; r++) oacc[j][r] *= alq[r];
        }

        // PV: A = P[q=ln16][key], B = V^T fragments (swizzled reads)
        short8 pa0 = *(const short8*)&Pw[wave][ln16 * 64 + (quad ^ sw) * 8];
        short8 pa1 = *(const short8*)&Pw[wave][ln16 * 64 + ((quad + 4) ^ sw) * 8];
        __builtin_amdgcn_s_setprio(1);
#pragma unroll
        for (int j = 0; j < 4; j++) {
            const int ro = (j * 16 + ln16) * 64;
            short8 b0 = *(const short8*)&VTs[ro + c0];
            short8 b1 = *(const short8*)&VTs[ro + c1];
            oacc[j] = __builtin_amdgcn_mfma_f32_16x16x32_bf16(pa0, b0, oacc[j], 0, 0, 0);
            oacc[j] = __builtin_amdgcn_mfma_f32_16x16x32_bf16(pa1, b1, oacc[j], 0, 0, 0);
        }
        __builtin_amdgcn_s_setprio(0);
    }

    // final cross-quad denominator reduction (once, not per tile)
    float l_run = l_lane;
    l_run += __shfl_xor(l_run, 16);
    l_run += __shfl_xor(l_run, 32);
    const float linv = 1.0f / l_run;
    float invq[4];
#pragma unroll
    for (int r = 0; r < 4; r++) invq[r] = __shfl(linv, quad * 4 + r);
#pragma unroll
    for (int r = 0; r < 4; r++) {
        const int row = bb * SEQ + q0 + wave * 16 + quad * 4 + r;
#pragma unroll
        for (int j = 0; j < 4; j++) {
            const int col = hh * 64 + j * 16 + ln16;
            catb[(size_t)row * E2DIM + col] = f2bu(oacc[j][r] * invq[r]);
        }
    }
}

// ---------------------------------------------------------------------------
// Host launch
// ---------------------------------------------------------------------------
extern "C" void kernel_launch(void* const* d_in, const int* in_sizes, int n_in,
                              void* d_out, int out_size, void* d_ws, size_t ws_size,
                              hipStream_t stream)
{
    // ---- workspace layout (float units) ----
    const size_t OFF_MT0 = 0;
    const size_t OFF_MT1 = OFF_MT0 + 131072;
    const size_t OFF_MT2 = OFF_MT1 + 131072;
    const size_t OFF_MT3 = OFF_MT2 + 131072;
    const size_t OFF_MT4 = OFF_MT3 + 131072;
    const size_t OFF_MT5 = OFF_MT4 + 524288;
    const size_t OFF_XB  = OFF_MT5 + 524288;        // x_bf / x1_bf (bf16 8192x512)
    const size_t OFF_CB  = OFF_XB + 2097152;        // cat bf16 [8192,1024]
    const size_t OFF_BQ  = OFF_CB + 4194304;        // q bf16 -> x2 bf16
    const size_t OFF_BN  = OFF_BQ + 4194304;        // fold t1 scratch -> VT -> h fp32
    const size_t OFF_BC  = OFF_BN + 4194304;        // fold t2 scratch -> x1 fp32
    const size_t OFF_P   = OFF_BC + 4194304;        // fp32-converted inputs

    float* W = (float*)d_ws;
    u16* MT[6] = {(u16*)(W + OFF_MT0), (u16*)(W + OFF_MT1), (u16*)(W + OFF_MT2),
                  (u16*)(W + OFF_MT3), (u16*)(W + OFF_MT4), (u16*)(W + OFF_MT5)};
    u16*   XB  = (u16*)(W + OFF_XB);
    u16*   CB  = (u16*)(W + OFF_CB);
    u16*   QB  = (u16*)(W + OFF_BQ);   // q bf16; later x2 bf16 (sequential reuse)
    float* BN  = W + OFF_BN;           // VT (during attn) -> h fp32 (after)
    float* BC  = W + OFF_BC;           // x1 fp32 (after fold)
    u16*   VT  = (u16*)BN;             // V^T bf16 [64][64][1024] (8 MB of 16 MB)

    float* F[23];
    CvtBatch cb;
    int pre = 0;
    for (int i = 0; i < 23 && i < n_in; i++) {
        cb.pre4[i] = pre;
        F[i] = W + OFF_P + (size_t)pre * 4;
        cb.src[i] = d_in[i];
        cb.dst[i] = (float4*)F[i];
        pre += in_sizes[i] / 4;
    }
    cb.pre4[23] = pre;
    const int total4 = pre;
    int* FLAG = (int*)(W + OFF_P + (size_t)total4 * 4);

    if (n_in < 23) return;
    if (ws_size < (OFF_P + (size_t)total4 * 4 + 16) * sizeof(float)) return;

    detect_dtype<<<1, 256, 0, stream>>>((const u16*)d_in[0], FLAG);
    cvt_all<<<(total4 + 255) / 256, 256, 0, stream>>>(cb, total4, FLAG);
    f2b_kernel<<<(ROWS * EDIM / 4 + 255) / 256, 256, 0, stream>>>(F[0], XB, ROWS * EDIM / 4);

    // ---- fold (3 batched launches): scratch overlays BN/BC (dead here) ----
    FoldBatch fb;
    {
        const int wi[6] = {1, 4, 7, 10, 13, 16};
        u16* T1 = (u16*)BN;
        u16* T2 = (u16*)BC;
        size_t off = 0;
        for (int s = 0; s < 6; s++) {
            const int n = (s < 4) ? 512 : 1024;
            fb.w[s]  = F[wi[s]];
            fb.fw[s] = F[wi[s] + 1];
            fb.t1[s] = T1 + off;
            fb.t2[s] = T2 + off;
            fb.mt[s] = MT[s];
            fb.n[s]  = n;
            fb.lg[s] = (s < 4) ? 9 : 10;
            fb.sc[s] = (s < 4) ? 0.04419417382415922f : 0.03125f;
            off += (size_t)n * n;
        }
    }
    fold_trconv<<<dim3(32, 32, 6), 256, 0, stream>>>(fb);
    fold_circ<<<dim3(4096, 1, 6), 256, 0, stream>>>(fb);
    fold_gemm<<<dim3(8, 8, 6), 256, 0, stream>>>(fb);

    float* out0 = (float*)d_out;                       // LN(h): [8192,512]
    float* out1 = (float*)d_out + (size_t)ROWS * EDIM; // out:   [8192,1024]

    // q = x @ M0 + attn_fb                                  -> QB (bf16)
    gemm_bf<<<dim3(8, 64), 256, 0, stream>>>(
        XB, 512, MT[0], 512, F[3], nullptr, 0, QB, 512, nullptr, 0, nullptr, 0, 512, 0);
    // V^T precompute (QB -> VT in BN region, dead until gemm_bf2 writes h)
    trans_vt<<<dim3(16, 2, 64), 256, 0, stream>>>(QB, VT);
    // attention -> cat bf16 [:, :512]
    attn_mfma<<<1024, 256, 0, stream>>>(QB, VT, CB);
    // x1 = LN(x + newx; n1)                                 -> BC fp32 + XB bf16
    ln_kernel<<<8192, 256, 0, stream>>>(F[0], 512, CB, 1024, F[19], F[20],
                                        BC, 512, XB, 512);
    // x_ln = gelu(x1 @ M1 + b); cat[:,512:]=bf16(v); x2=bf16(x1-v) -> QB
    gemm_bf<<<dim3(8, 64), 256, 0, stream>>>(
        XB, 512, MT[1], 512, F[6], nullptr, 0, CB + 512, 1024, QB, 512, BC, 512, 512, 1);
    // h = sigmoid(x2@M2+b2) * (x2@M3+b3)                     -> BN fp32
    gemm_bf2<<<dim3(8, 64), 256, 0, stream>>>(
        QB, 512, MT[2], MT[3], 512, F[9], F[12], BN, 512, 512);
    // out0 = LN(h; n2)                                       -> d_out
    ln_kernel<<<8192, 256, 0, stream>>>(BN, 512, nullptr, 0, F[21], F[22],
                                        out0, 512, nullptr, 0);
    // out1 = sigmoid(cat@M4+b4) * (cat@M5+b5)                -> d_out+4M
    gemm_bf2<<<dim3(16, 64), 256, 0, stream>>>(
        CB, 1024, MT[4], MT[5], 1024, F[15], F[18], out1, 1024, 1024);
}

// Round 17
// 321.719 us; speedup vs baseline: 1.0286x; 1.0125x over previous
//
#include <hip/hip_runtime.h>
#include <hip/hip_bf16.h>
#include <math.h>

typedef __hip_bfloat16 bf16;
typedef unsigned short u16;
typedef __attribute__((ext_vector_type(8))) short short8;
typedef __attribute__((ext_vector_type(4))) float f32x4;

#define NB      8
#define SEQ     1024
#define EDIM    512
#define E2DIM   1024
#define ROWS    8192
#define INV_SQRT_E 0.04419417382415922f
#define ATT_SCL    0.06375985678148161f   /* INV_SQRT_E * log2(e) */

__device__ inline u16 f2bu(float f) {           // fp32 -> bf16 bits, RNE
    union { float f; unsigned u; } c; c.f = f;
    return (u16)((c.u + 0x7FFF + ((c.u >> 16) & 1)) >> 16);
}

__device__ __forceinline__ unsigned cvtpk_bf16(float lo, float hi) {
    unsigned r;
    asm("v_cvt_pk_bf16_f32 %0, %1, %2" : "=v"(r) : "v"(lo), "v"(hi));
    return r;
}

// counted-vmcnt pipeline fence (T4): loads stay in flight across barriers.
#define VMCNT(N) do { \
    asm volatile("s_waitcnt vmcnt(" #N ")" ::: "memory"); \
    __builtin_amdgcn_sched_barrier(0); \
    __builtin_amdgcn_s_barrier(); \
    __builtin_amdgcn_sched_barrier(0); } while (0)

__device__ __forceinline__ void dma16(const u16* g, u16* l) {
    __builtin_amdgcn_global_load_lds(
        (const __attribute__((address_space(1))) void*)g,
        (__attribute__((address_space(3))) void*)l, 16, 0, 0);
}

// ---------------------------------------------------------------------------
// Input dtype autodetect (proved inputs are fp32; kept as cheap insurance).
// ---------------------------------------------------------------------------
__global__ __launch_bounds__(256) void detect_dtype(const u16* __restrict__ x,
                                                    int* __restrict__ flag) {
    int t = threadIdx.x;
    int cnt = 0;
    for (int k = t; k < 8192; k += 256) {
        int e = (x[k] >> 7) & 0xFF;
        if (e >= 0xC0) cnt++;
    }
#pragma unroll
    for (int o = 32; o > 0; o >>= 1) cnt += __shfl_xor(cnt, o);
    __shared__ int red[4];
    if ((t & 63) == 0) red[t >> 6] = cnt;
    __syncthreads();
    if (t == 0) flag[0] = (red[0] + red[1] + red[2] + red[3] > 100) ? 1 : 0;
}

// ---------------------------------------------------------------------------
// Batch conversion of all 23 inputs -> fp32 workspace (dtype-adaptive).
// Input 0 (x) additionally emits bf16 into xb (fuses the old f2b_kernel:
// same f2bu RNE conversion -> bit-exact; saves a 16 MB re-read + a launch).
// ---------------------------------------------------------------------------
struct CvtBatch {
    const void* src[23];
    float4*     dst[23];
    int         pre4[24];
};

__global__ __launch_bounds__(256) void cvt_all(CvtBatch a, int total4,
                                               const int* __restrict__ flag,
                                               u16* __restrict__ xb) {
    int t = blockIdx.x * 256 + threadIdx.x;
    if (t >= total4) return;
    int lo = 0;
    while (t >= a.pre4[lo + 1]) lo++;
    int li = t - a.pre4[lo];
    if (flag[0]) {
        float4 v = ((const float4*)a.src[lo])[li];
        a.dst[lo][li] = v;
        if (lo == 0) {
            ushort4 o;
            o.x = f2bu(v.x); o.y = f2bu(v.y); o.z = f2bu(v.z); o.w = f2bu(v.w);
            ((ushort4*)xb)[li] = o;
        }
    } else {
        ushort4 u = ((const ushort4*)a.src[lo])[li];
        union { unsigned int i; float f; } c;
        float4 o;
        c.i = ((unsigned)u.x) << 16; o.x = c.f;
        c.i = ((unsigned)u.y) << 16; o.y = c.f;
        c.i = ((unsigned)u.z) << 16; o.z = c.f;
        c.i = ((unsigned)u.w) << 16; o.w = c.f;
        a.dst[lo][li] = o;
        if (lo == 0) ((ushort4*)xb)[li] = u;   // already bf16 bits
    }
}

#define LDK 32   /* linear LDS row: 32 bf16 = 64 B = 4 chunks of 16 B */

// Bijective XCD-aware block swizzle (requires gridDim.x*gridDim.y % 8 == 0).
__device__ __forceinline__ void xcd_swz(int& bx, int& by) {
    const int nx  = gridDim.x;
    const int nwg = nx * gridDim.y;
    const int lid = blockIdx.y * nx + blockIdx.x;
    const int q   = nwg >> 3;
    const int s   = (lid & 7) * q + (lid >> 3);
    bx = s % nx;
    by = s / nx;
}

// ---------------------------------------------------------------------------
// Fold batch: 6 spectral layers, z-indexed kernels (3 launches total).
// ---------------------------------------------------------------------------
struct FoldBatch {
    const float* w[6];
    const float* fw[6];
    u16* t1[6];
    u16* t2[6];
    u16* mt[6];
    int  n[6], lg[6];
    float sc[6];
};

__global__ __launch_bounds__(256) void fold_trconv(FoldBatch fb) {
    const int z = blockIdx.z;
    const int n = fb.n[z];
    const int bx = blockIdx.x * 32, by = blockIdx.y * 32;
    if (bx >= n || by >= n) return;
    __shared__ float t[32][33];
    const int tx = threadIdx.x & 31, ty = threadIdx.x >> 5;   // 32x8
    const float* src = fb.fw[z];
    u16* dst = fb.t1[z];
#pragma unroll
    for (int r = 0; r < 32; r += 8)
        t[ty + r][tx] = src[(size_t)(by + ty + r) * n + bx + tx];
    __syncthreads();
#pragma unroll
    for (int r = 0; r < 32; r += 8)
        dst[(size_t)(bx + ty + r) * n + by + tx] = f2bu(t[tx][ty + r]);
}

__global__ __launch_bounds__(256) void fold_circ(FoldBatch fb) {
    const int z = blockIdx.z;
    const int n = fb.n[z], lg = fb.lg[z];
    int idx = blockIdx.x * 256 + threadIdx.x;
    if (idx >= n * n) return;
    int mask = n - 1;
    int m = idx & mask;
    int j = idx >> lg;
    fb.t2[z][idx] = f2bu(fb.w[z][(m - j) & mask]);
}

// 3-buffer single-barrier pipeline, hoisted staging addresses.
__global__ __launch_bounds__(256) void fold_gemm(FoldBatch fb) {
    const int z = blockIdx.z;
    const int n = fb.n[z];
    const int bm = blockIdx.y * 128, bn = blockIdx.x * 128;
    if (bm >= n || bn >= n) return;
    const u16* A  = fb.t1[z];
    const u16* Bt = fb.t2[z];
    u16* Mt = fb.mt[z];
    const float scale = fb.sc[z];

    __shared__ u16 Asl[3][128 * LDK];
    __shared__ u16 Bsl[3][128 * LDK];
    const int tid = threadIdx.x;
    const int lane = tid & 63, wave = tid >> 6;
    const int wy = wave >> 1, wx = wave & 1;
    const int qd = lane >> 4, ln16 = lane & 15;
    const int ca = (qd ^ ((ln16 >> 1) & 3)) * 8;   // swizzled read chunk

    const int srow = wave * 16 + (lane >> 2);
    const int scol = ((lane & 3) ^ ((lane >> 3) & 3)) * 8;
    const int lo   = wave * 16 * LDK;
    const size_t a64 = (size_t)64 * n;
    const u16* pA = A  + (size_t)bm * n + (size_t)srow * n + scol;
    const u16* pB = Bt + (size_t)bn * n + (size_t)srow * n + scol;

    f32x4 acc[4][4];
#pragma unroll
    for (int i = 0; i < 4; i++)
#pragma unroll
        for (int j = 0; j < 4; j++)
#pragma unroll
            for (int r = 0; r < 4; r++) acc[i][j][r] = 0.f;

#define STAGE_FG(bi) do { \
    dma16(pA,       &Asl[bi][lo]); \
    dma16(pA + a64, &Asl[bi][lo + 64 * LDK]); \
    dma16(pB,       &Bsl[bi][lo]); \
    dma16(pB + a64, &Bsl[bi][lo + 64 * LDK]); \
    pA += 32; pB += 32; } while (0)

    const int nt = n >> 5;
    STAGE_FG(0);
    STAGE_FG(1);
    int cur = 0, stg = 2;
    for (int t = 0; t < nt; ++t) {
        if (t < nt - 1) { VMCNT(4); } else { VMCNT(0); }
        const u16* Ac = Asl[cur];
        const u16* Bc = Bsl[cur];
        short8 af[4], bf_[4];
#pragma unroll
        for (int i = 0; i < 4; i++) {
            af[i]  = *(const short8*)&Ac[(wy * 64 + i * 16 + ln16) * LDK + ca];
            bf_[i] = *(const short8*)&Bc[(wx * 64 + i * 16 + ln16) * LDK + ca];
        }
        if (t + 2 < nt) STAGE_FG(stg);
#pragma unroll
        for (int i = 0; i < 4; i++)
#pragma unroll
            for (int j = 0; j < 4; j++)
                acc[i][j] = __builtin_amdgcn_mfma_f32_16x16x32_bf16(af[i], bf_[j], acc[i][j], 0, 0, 0);
        cur = (cur == 2) ? 0 : cur + 1;
        stg = (stg == 2) ? 0 : stg + 1;
    }
#undef STAGE_FG
#pragma unroll
    for (int i = 0; i < 4; i++)
#pragma unroll
        for (int j = 0; j < 4; j++) {
            const int col = bn + wx * 64 + j * 16 + ln16;
#pragma unroll
            for (int r = 0; r < 4; r++) {
                const int row = bm + wy * 64 + i * 16 + qd * 4 + r;
                Mt[(size_t)row * n + col] = f2bu(acc[i][j][r] * scale);
            }
        }
}

// ---------------------------------------------------------------------------
// bf16 MFMA GEMM (single B): C = act( A @ B + bias ). B pre-transposed.
// 128x64 tile, BK=32, 3-buffer single-barrier pipeline, swizzled LDS.
// ---------------------------------------------------------------------------
__global__ __launch_bounds__(256) void gemm_bf(
    const u16* __restrict__ A, int lda,
    const u16* __restrict__ Bt, int ldb,
    const float* __restrict__ bias,
    float* __restrict__ Cf, int ldc,
    u16* __restrict__ Cb, int ldcb,
    u16* __restrict__ Cb2, int ldcb2,
    const float* __restrict__ aux, int ldaux,
    int K, int mode)
{
    __shared__ u16 Asl[3][128 * LDK];
    __shared__ u16 Bsl[3][64 * LDK];
    const int tid = threadIdx.x;
    int bxs, bys;
    xcd_swz(bxs, bys);
    const int bm = bys * 128, bn = bxs * 64;
    const int lane = tid & 63, wave = tid >> 6;
    const int wy = wave >> 1, wx = wave & 1;
    const int qd = lane >> 4, ln16 = lane & 15;
    const int ca = (qd ^ ((ln16 >> 1) & 3)) * 8;

    const int srow = wave * 16 + (lane >> 2);
    const int scol = ((lane & 3) ^ ((lane >> 3) & 3)) * 8;
    const int lo   = wave * 16 * LDK;
    const size_t a64 = (size_t)64 * lda;
    const u16* pA = A  + (size_t)bm * lda + (size_t)srow * lda + scol;
    const u16* pB = Bt + (size_t)bn * ldb + (size_t)srow * ldb + scol;

    f32x4 acc[4][2];
#pragma unroll
    for (int i = 0; i < 4; i++)
#pragma unroll
        for (int j = 0; j < 2; j++)
#pragma unroll
            for (int r = 0; r < 4; r++) acc[i][j][r] = 0.f;

#define STAGE_GB(bi) do { \
    dma16(pA,       &Asl[bi][lo]); \
    dma16(pA + a64, &Asl[bi][lo + 64 * LDK]); \
    dma16(pB,       &Bsl[bi][lo]); \
    pA += 32; pB += 32; } while (0)

    const int nt = K >> 5;
    STAGE_GB(0);
    STAGE_GB(1);
    int cur = 0, stg = 2;
    for (int t = 0; t < nt; ++t) {
        if (t < nt - 1) { VMCNT(3); } else { VMCNT(0); }
        const u16* Ac = Asl[cur];
        const u16* Bc = Bsl[cur];
        short8 af[4], bf_[2];
#pragma unroll
        for (int i = 0; i < 4; i++)
            af[i]  = *(const short8*)&Ac[(wy * 64 + i * 16 + ln16) * LDK + ca];
#pragma unroll
        for (int j = 0; j < 2; j++)
            bf_[j] = *(const short8*)&Bc[(wx * 32 + j * 16 + ln16) * LDK + ca];
        if (t + 2 < nt) STAGE_GB(stg);
#pragma unroll
        for (int i = 0; i < 4; i++)
#pragma unroll
            for (int j = 0; j < 2; j++)
                acc[i][j] = __builtin_amdgcn_mfma_f32_16x16x32_bf16(af[i], bf_[j], acc[i][j], 0, 0, 0);
        cur = (cur == 2) ? 0 : cur + 1;
        stg = (stg == 2) ? 0 : stg + 1;
    }
#undef STAGE_GB

#pragma unroll
    for (int i = 0; i < 4; i++) {
#pragma unroll
        for (int j = 0; j < 2; j++) {
            const int col = bn + wx * 32 + j * 16 + ln16;
            const float b_ = bias ? bias[col] : 0.f;
#pragma unroll
            for (int r = 0; r < 4; r++) {
                const int row = bm + wy * 64 + i * 16 + qd * 4 + r;
                float v = acc[i][j][r] + b_;
                if (mode == 1) v = 0.5f * v * (1.0f + erff(v * 0.7071067811865476f));
                if (Cf)  Cf[(size_t)row * ldc + col] = v;
                if (Cb)  Cb[(size_t)row * ldcb + col] = f2bu(v);
                if (Cb2) Cb2[(size_t)row * ldcb2 + col] =
                             f2bu(aux[(size_t)row * ldaux + col] - v);
            }
        }
    }
}

// ---------------------------------------------------------------------------
// Dual-B fused gate GEMM: C = sigmoid(A@B1 + b1) * (A@B2 + b2), fp32 out.
// 128x64 tile, 3-buffer single-barrier pipeline, swizzled LDS.
// ---------------------------------------------------------------------------
__global__ __launch_bounds__(256) void gemm_bf2(
    const u16* __restrict__ A, int lda,
    const u16* __restrict__ B1t, const u16* __restrict__ B2t, int ldb,
    const float* __restrict__ bias1, const float* __restrict__ bias2,
    float* __restrict__ Cf, int ldc, int K)
{
    __shared__ u16 Asl[3][128 * LDK];
    __shared__ u16 B1sl[3][64 * LDK];
    __shared__ u16 B2sl[3][64 * LDK];
    const int tid = threadIdx.x;
    int bxs, bys;
    xcd_swz(bxs, bys);
    const int bm = bys * 128, bn = bxs * 64;
    const int lane = tid & 63, wave = tid >> 6;
    const int wy = wave >> 1, wx = wave & 1;
    const int qd = lane >> 4, ln16 = lane & 15;
    const int ca = (qd ^ ((ln16 >> 1) & 3)) * 8;

    const int srow = wave * 16 + (lane >> 2);
    const int scol = ((lane & 3) ^ ((lane >> 3) & 3)) * 8;
    const int lo   = wave * 16 * LDK;
    const size_t a64 = (size_t)64 * lda;
    const u16* pA  = A   + (size_t)bm * lda + (size_t)srow * lda + scol;
    const u16* pB1 = B1t + (size_t)bn * ldb + (size_t)srow * ldb + scol;
    const u16* pB2 = B2t + (size_t)bn * ldb + (size_t)srow * ldb + scol;

    f32x4 acc1[4][2], acc2[4][2];
#pragma unroll
    for (int i = 0; i < 4; i++)
#pragma unroll
        for (int j = 0; j < 2; j++)
#pragma unroll
            for (int r = 0; r < 4; r++) { acc1[i][j][r] = 0.f; acc2[i][j][r] = 0.f; }

#define STAGE_GB2(bi) do { \
    dma16(pA,       &Asl[bi][lo]); \
    dma16(pA + a64, &Asl[bi][lo + 64 * LDK]); \
    dma16(pB1,      &B1sl[bi][lo]); \
    dma16(pB2,      &B2sl[bi][lo]); \
    pA += 32; pB1 += 32; pB2 += 32; } while (0)

    const int nt = K >> 5;
    STAGE_GB2(0);
    STAGE_GB2(1);
    int cur = 0, stg = 2;
    for (int t = 0; t < nt; ++t) {
        if (t < nt - 1) { VMCNT(4); } else { VMCNT(0); }
        const u16* Ac  = Asl[cur];
        const u16* B1c = B1sl[cur];
        const u16* B2c = B2sl[cur];
        short8 af[4], b1f[2], b2f[2];
#pragma unroll
        for (int i = 0; i < 4; i++)
            af[i]  = *(const short8*)&Ac [(wy * 64 + i * 16 + ln16) * LDK + ca];
#pragma unroll
        for (int j = 0; j < 2; j++) {
            b1f[j] = *(const short8*)&B1c[(wx * 32 + j * 16 + ln16) * LDK + ca];
            b2f[j] = *(const short8*)&B2c[(wx * 32 + j * 16 + ln16) * LDK + ca];
        }
        if (t + 2 < nt) STAGE_GB2(stg);
#pragma unroll
        for (int i = 0; i < 4; i++)
#pragma unroll
            for (int j = 0; j < 2; j++) {
                acc1[i][j] = __builtin_amdgcn_mfma_f32_16x16x32_bf16(af[i], b1f[j], acc1[i][j], 0, 0, 0);
                acc2[i][j] = __builtin_amdgcn_mfma_f32_16x16x32_bf16(af[i], b2f[j], acc2[i][j], 0, 0, 0);
            }
        cur = (cur == 2) ? 0 : cur + 1;
        stg = (stg == 2) ? 0 : stg + 1;
    }
#undef STAGE_GB2

#pragma unroll
    for (int i = 0; i < 4; i++) {
#pragma unroll
        for (int j = 0; j < 2; j++) {
            const int col = bn + wx * 32 + j * 16 + ln16;
            const float b1_ = bias1[col], b2_ = bias2[col];
#pragma unroll
            for (int r = 0; r < 4; r++) {
                const int row = bm + wy * 64 + i * 16 + qd * 4 + r;
                const float g = 1.0f / (1.0f + expf(-(acc1[i][j][r] + b1_)));
                Cf[(size_t)row * ldc + col] = g * (acc2[i][j][r] + b2_);
            }
        }
    }
}

// ---------------------------------------------------------------------------
// LayerNorm over 512 features. in1b optional bf16 add. fp32 + optional bf16 out.
// ---------------------------------------------------------------------------
__global__ __launch_bounds__(256) void ln_kernel(
    const float* __restrict__ in0, int ld0,
    const u16* __restrict__ in1b, int ld1b,
    const float* __restrict__ g, const float* __restrict__ bta,
    float* __restrict__ outf, int ldo,
    u16* __restrict__ outb, int ldob)
{
    int row = blockIdx.x, tid = threadIdx.x;
    const float* p0 = in0 + (size_t)row * ld0;
    float v0 = p0[tid], v1 = p0[tid + 256];
    if (in1b) {
        const u16* p1 = in1b + (size_t)row * ld1b;
        union { unsigned u; float f; } c0, c1;
        c0.u = ((unsigned)p1[tid]) << 16;
        c1.u = ((unsigned)p1[tid + 256]) << 16;
        v0 += c0.f; v1 += c1.f;
    }
    float s = v0 + v1, sq = v0 * v0 + v1 * v1;
#pragma unroll
    for (int o = 32; o > 0; o >>= 1) {
        s  += __shfl_xor(s, o);
        sq += __shfl_xor(sq, o);
    }
    __shared__ float red[8];
    int wid = tid >> 6;
    if ((tid & 63) == 0) { red[wid] = s; red[4 + wid] = sq; }
    __syncthreads();
    s  = red[0] + red[1] + red[2] + red[3];
    sq = red[4] + red[5] + red[6] + red[7];
    float mean = s * (1.0f / 512.0f);
    float var  = sq * (1.0f / 512.0f) - mean * mean;
    float rstd = rsqrtf(var + 1e-5f);
    float o0 = (v0 - mean) * rstd * g[tid] + bta[tid];
    float o1 = (v1 - mean) * rstd * g[tid + 256] + bta[tid + 256];
    if (outf) {
        outf[(size_t)row * ldo + tid]       = o0;
        outf[(size_t)row * ldo + tid + 256] = o1;
    }
    if (outb) {
        outb[(size_t)row * ldob + tid]       = f2bu(o0);
        outb[(size_t)row * ldob + tid + 256] = f2bu(o1);
    }
}

// ---------------------------------------------------------------------------
// V^T precompute: vt[(bb*8+hh)][d=64][key=1024] = q[bb*1024+key][hh*64+d].
// LDS-tiled, coalesced both sides. Bit-exact copy.
// ---------------------------------------------------------------------------
__global__ __launch_bounds__(256) void trans_vt(const u16* __restrict__ q,
                                                u16* __restrict__ vt) {
    const int z  = blockIdx.z;            // bb*8+hh
    const int bb = z >> 3, hh = z & 7;
    const int k0 = blockIdx.x * 64;       // key tile
    const int d0 = blockIdx.y * 32;       // d tile
    __shared__ u16 t[64][33];
    const int tx = threadIdx.x & 31, ty = threadIdx.x >> 5;   // 32 x 8
    const u16* src = q + (size_t)(bb * SEQ + k0) * EDIM + hh * 64 + d0;
#pragma unroll
    for (int r = 0; r < 64; r += 8)
        t[ty + r][tx] = src[(size_t)(ty + r) * EDIM + tx];
    __syncthreads();
    const int ox = threadIdx.x & 63, oy = threadIdx.x >> 6;   // 64 x 4
    u16* dst = vt + ((size_t)z * 64 + d0) * SEQ + k0;
#pragma unroll
    for (int r = 0; r < 32; r += 4)
        dst[(size_t)(oy + r) * SEQ + ox] = t[ox][oy + r];
}

// ---------------------------------------------------------------------------
// MFMA flash attention, q==k==v bf16, head_dim 64. exp2-domain softmax.
// S^T orientation; K and precomputed V^T staged via swizzled global_load_lds.
// Single-buffer (24.5 KB LDS -> 4 blocks/CU), XCD-swizzled block ids.
// Lane-local l accumulation; gated max reduction (bit-exact skips).
// Pw at AP=64 with 16B-block XOR swizzle (bank-conflict-free).
// s_setprio(1) around MFMA clusters (T5: cross-block arbitration).
// Writes bf16 new_x into catb[:, 0:512] (ld 1024).
// ---------------------------------------------------------------------------
#define ANT 16  /* SEQ/64 k-tiles */

__global__ __launch_bounds__(256) void attn_mfma(const u16* __restrict__ qall,
                                                 const u16* __restrict__ vt,
                                                 u16* __restrict__ catb) {
    __shared__ u16 Ks[64 * 64];         // [key][d]  chunk-swizzled rows (8 KB)
    __shared__ u16 VTs[64 * 64];        // [d][key]  chunk-swizzled rows (8 KB)
    __shared__ u16 Pw[4][16 * 64];      // per-wave P, block-swizzled (8 KB)

    const int phys = blockIdx.x;
    const int bid = (phys & 7) * 128 + (phys >> 3);  // XCD-contiguous logical id
    const int lt = bid & 15, hh = (bid >> 4) & 7, bb = bid >> 7;
    const int q0 = lt * 64;
    const int tid = threadIdx.x;
    const int wave = tid >> 6, lane = tid & 63;
    const int quad = lane >> 4, ln16 = lane & 15;

    const u16* qh = qall + (size_t)bb * SEQ * EDIM + hh * 64;
    const u16* vh = vt + (size_t)(bb * 8 + hh) * 64 * SEQ;

    const u16* qrow = qh + (size_t)(q0 + wave * 16 + ln16) * EDIM + quad * 8;
    const short8 aq0 = *(const short8*)(qrow);
    const short8 aq1 = *(const short8*)(qrow + 32);

    f32x4 oacc[4];
    float m_run = -1e30f;                // running max for q = ln16 (uniform/quad)
    float l_lane = 0.f;                  // lane-local partial denominator
#pragma unroll
    for (int j = 0; j < 4; j++)
#pragma unroll
        for (int r = 0; r < 4; r++) oacc[j][r] = 0.f;

    const int sw = ln16 & 7;             // row&7 for rows j*16+ln16
    const int c0 = (quad ^ sw) * 8;
    const int c1 = ((quad + 4) ^ sw) * 8;

    // hoisted staging geometry (chunk-XOR swizzle on global source)
    const int r0  = wave * 16 + (lane >> 3);
    const int r1  = r0 + 8;
    const int cg0 = (lane & 7) ^ (r0 & 7);
    const int cg1 = (lane & 7) ^ (r1 & 7);
    const u16* pK0 = qh + (size_t)r0 * EDIM + cg0 * 8;
    const u16* pK1 = qh + (size_t)r1 * EDIM + cg1 * 8;
    const u16* pV0 = vh + (size_t)r0 * SEQ + cg0 * 8;
    const u16* pV1 = vh + (size_t)r1 * SEQ + cg1 * 8;
    const int lds0 = (wave * 16) * 64;          // wave-uniform LDS bases
    const int lds1 = (wave * 16 + 8) * 64;

    for (int t = 0; t < ANT; ++t) {
        if (t) __syncthreads();          // all waves done reading prev tile
        dma16(pK0 + (size_t)t * 64 * EDIM, &Ks[lds0]);
        dma16(pK1 + (size_t)t * 64 * EDIM, &Ks[lds1]);
        dma16(pV0 + t * 64, &VTs[lds0]);
        dma16(pV1 + t * 64, &VTs[lds1]);
        __syncthreads();                 // drains DMA (vmcnt) + joins

        // QK^T: S^T[j] lane(quad,ln16) reg r = scores[key=j*16+quad*4+r][q=ln16]
        f32x4 S[4];
        __builtin_amdgcn_s_setprio(1);
#pragma unroll
        for (int j = 0; j < 4; j++) {
            const int ro = (j * 16 + ln16) * 64;
            short8 a0 = *(const short8*)&Ks[ro + c0];
            short8 a1 = *(const short8*)&Ks[ro + c1];
            f32x4 c = {0.f, 0.f, 0.f, 0.f};
            c = __builtin_amdgcn_mfma_f32_16x16x32_bf16(a0, aq0, c, 0, 0, 0);
            c = __builtin_amdgcn_mfma_f32_16x16x32_bf16(a1, aq1, c, 0, 0, 0);
            S[j] = c;
        }
        __builtin_amdgcn_s_setprio(0);

        // local max over this lane's 16 keys
        float mxl = S[0][0];
#pragma unroll
        for (int j = 0; j < 4; j++)
#pragma unroll
            for (int r = 0; r < 4; r++) mxl = fmaxf(mxl, S[j][r]);

        // gated cross-quad max reduce (wave-uniform decision; bit-exact skip)
        const bool newm = __any(mxl > m_run);
        float al = 1.0f;
        if (newm) {
            float mx = fmaxf(mxl, __shfl_xor(mxl, 16));
            mx = fmaxf(mx, __shfl_xor(mx, 32));
            const float mn = fmaxf(m_run, mx);
            al = exp2f((m_run - mn) * ATT_SCL);
            m_run = mn;
        }
        const float ns = -m_run * ATT_SCL;
        float p[4][4];
        float rsl = 0.f;
#pragma unroll
        for (int j = 0; j < 4; j++)
#pragma unroll
            for (int r = 0; r < 4; r++) {
                p[j][r] = exp2f(fmaf(S[j][r], ATT_SCL, ns));
                rsl += p[j][r];
            }
        l_lane = l_lane * al + rsl;      // lane-local; cross-quad sum at end

        // pack P -> Pw[wave], row q=ln16, 16B-block b stored at b^sw.
        // key j*16+quad*4 -> block j*2+(quad>>1), 8B-half quad&1.
#pragma unroll
        for (int j = 0; j < 4; j++) {
            unsigned w0 = cvtpk_bf16(p[j][0], p[j][1]);
            unsigned w1 = cvtpk_bf16(p[j][2], p[j][3]);
            const int blk = (j * 2 + (quad >> 1)) ^ sw;
            *(uint2*)&Pw[wave][ln16 * 64 + blk * 8 + (quad & 1) * 4] =
                make_uint2(w0, w1);
        }

        // rescale O only when a new max appeared (bit-exact skip otherwise)
        if (newm) {
            float alq[4];
#pragma unroll
            for (int r = 0; r < 4; r++) alq[r] = __shfl(al, quad * 4 + r);
#pragma unroll
            for (int j = 0; j < 4; j++)
#pragma unroll
                for (int r = 0; r < 4; r++) oacc[j][r] *= alq[r];
        }

        // PV: A = P[q=ln16][key], B = V^T fragments (swizzled reads)
        short8 pa0 = *(const short8*)&Pw[wave][ln16 * 64 + (quad ^ sw) * 8];
        short8 pa1 = *(const short8*)&Pw[wave][ln16 * 64 + ((quad + 4) ^ sw) * 8];
        __builtin_amdgcn_s_setprio(1);
#pragma unroll
        for (int j = 0; j < 4; j++) {
            const int ro = (j * 16 + ln16) * 64;
            short8 b0 = *(const short8*)&VTs[ro + c0];
            short8 b1 = *(const short8*)&VTs[ro + c1];
            oacc[j] = __builtin_amdgcn_mfma_f32_16x16x32_bf16(pa0, b0, oacc[j], 0, 0, 0);
            oacc[j] = __builtin_amdgcn_mfma_f32_16x16x32_bf16(pa1, b1, oacc[j], 0, 0, 0);
        }
        __builtin_amdgcn_s_setprio(0);
    }

    // final cross-quad denominator reduction (once, not per tile)
    float l_run = l_lane;
    l_run += __shfl_xor(l_run, 16);
    l_run += __shfl_xor(l_run, 32);
    const float linv = 1.0f / l_run;
    float invq[4];
#pragma unroll
    for (int r = 0; r < 4; r++) invq[r] = __shfl(linv, quad * 4 + r);
#pragma unroll
    for (int r = 0; r < 4; r++) {
        const int row = bb * SEQ + q0 + wave * 16 + quad * 4 + r;
#pragma unroll
        for (int j = 0; j < 4; j++) {
            const int col = hh * 64 + j * 16 + ln16;
            catb[(size_t)row * E2DIM + col] = f2bu(oacc[j][r] * invq[r]);
        }
    }
}

// ---------------------------------------------------------------------------
// Host launch
// ---------------------------------------------------------------------------
extern "C" void kernel_launch(void* const* d_in, const int* in_sizes, int n_in,
                              void* d_out, int out_size, void* d_ws, size_t ws_size,
                              hipStream_t stream)
{
    // ---- workspace layout (float units) ----
    const size_t OFF_MT0 = 0;
    const size_t OFF_MT1 = OFF_MT0 + 131072;
    const size_t OFF_MT2 = OFF_MT1 + 131072;
    const size_t OFF_MT3 = OFF_MT2 + 131072;
    const size_t OFF_MT4 = OFF_MT3 + 131072;
    const size_t OFF_MT5 = OFF_MT4 + 524288;
    const size_t OFF_XB  = OFF_MT5 + 524288;        // x_bf / x1_bf (bf16 8192x512)
    const size_t OFF_CB  = OFF_XB + 2097152;        // cat bf16 [8192,1024]
    const size_t OFF_BQ  = OFF_CB + 4194304;        // q bf16 -> x2 bf16
    const size_t OFF_BN  = OFF_BQ + 4194304;        // fold t1 scratch -> VT -> h fp32
    const size_t OFF_BC  = OFF_BN + 4194304;        // fold t2 scratch -> x1 fp32
    const size_t OFF_P   = OFF_BC + 4194304;        // fp32-converted inputs

    float* W = (float*)d_ws;
    u16* MT[6] = {(u16*)(W + OFF_MT0), (u16*)(W + OFF_MT1), (u16*)(W + OFF_MT2),
                  (u16*)(W + OFF_MT3), (u16*)(W + OFF_MT4), (u16*)(W + OFF_MT5)};
    u16*   XB  = (u16*)(W + OFF_XB);
    u16*   CB  = (u16*)(W + OFF_CB);
    u16*   QB  = (u16*)(W + OFF_BQ);   // q bf16; later x2 bf16 (sequential reuse)
    float* BN  = W + OFF_BN;           // VT (during attn) -> h fp32 (after)
    float* BC  = W + OFF_BC;           // x1 fp32 (after fold)
    u16*   VT  = (u16*)BN;             // V^T bf16 [64][64][1024] (8 MB of 16 MB)

    float* F[23];
    CvtBatch cb;
    int pre = 0;
    for (int i = 0; i < 23 && i < n_in; i++) {
        cb.pre4[i] = pre;
        F[i] = W + OFF_P + (size_t)pre * 4;
        cb.src[i] = d_in[i];
        cb.dst[i] = (float4*)F[i];
        pre += in_sizes[i] / 4;
    }
    cb.pre4[23] = pre;
    const int total4 = pre;
    int* FLAG = (int*)(W + OFF_P + (size_t)total4 * 4);

    if (n_in < 23) return;
    if (ws_size < (OFF_P + (size_t)total4 * 4 + 16) * sizeof(float)) return;

    detect_dtype<<<1, 256, 0, stream>>>((const u16*)d_in[0], FLAG);
    // cvt_all also emits bf16(x) into XB (fused f2b)
    cvt_all<<<(total4 + 255) / 256, 256, 0, stream>>>(cb, total4, FLAG, XB);

    // ---- fold (3 batched launches): scratch overlays BN/BC (dead here) ----
    FoldBatch fb;
    {
        const int wi[6] = {1, 4, 7, 10, 13, 16};
        u16* T1 = (u16*)BN;
        u16* T2 = (u16*)BC;
        size_t off = 0;
        for (int s = 0; s < 6; s++) {
            const int n = (s < 4) ? 512 : 1024;
            fb.w[s]  = F[wi[s]];
            fb.fw[s] = F[wi[s] + 1];
            fb.t1[s] = T1 + off;
            fb.t2[s] = T2 + off;
            fb.mt[s] = MT[s];
            fb.n[s]  = n;
            fb.lg[s] = (s < 4) ? 9 : 10;
            fb.sc[s] = (s < 4) ? 0.04419417382415922f : 0.03125f;
            off += (size_t)n * n;
        }
    }
    fold_trconv<<<dim3(32, 32, 6), 256, 0, stream>>>(fb);
    fold_circ<<<dim3(4096, 1, 6), 256, 0, stream>>>(fb);
    fold_gemm<<<dim3(8, 8, 6), 256, 0, stream>>>(fb);

    float* out0 = (float*)d_out;                       // LN(h): [8192,512]
    float* out1 = (float*)d_out + (size_t)ROWS * EDIM; // out:   [8192,1024]

    // q = x @ M0 + attn_fb                                  -> QB (bf16)
    gemm_bf<<<dim3(8, 64), 256, 0, stream>>>(
        XB, 512, MT[0], 512, F[3], nullptr, 0, QB, 512, nullptr, 0, nullptr, 0, 512, 0);
    // V^T precompute (QB -> VT in BN region, dead until gemm_bf2 writes h)
    trans_vt<<<dim3(16, 2, 64), 256, 0, stream>>>(QB, VT);
    // attention -> cat bf16 [:, :512]
    attn_mfma<<<1024, 256, 0, stream>>>(QB, VT, CB);
    // x1 = LN(x + newx; n1)                                 -> BC fp32 + XB bf16
    ln_kernel<<<8192, 256, 0, stream>>>(F[0], 512, CB, 1024, F[19], F[20],
                                        BC, 512, XB, 512);
    // x_ln = gelu(x1 @ M1 + b); cat[:,512:]=bf16(v); x2=bf16(x1-v) -> QB
    gemm_bf<<<dim3(8, 64), 256, 0, stream>>>(
        XB, 512, MT[1], 512, F[6], nullptr, 0, CB + 512, 1024, QB, 512, BC, 512, 512, 1);
    // h = sigmoid(x2@M2+b2) * (x2@M3+b3)                     -> BN fp32
    gemm_bf2<<<dim3(8, 64), 256, 0, stream>>>(
        QB, 512, MT[2], MT[3], 512, F[9], F[12], BN, 512, 512);
    // out0 = LN(h; n2)                                       -> d_out
    ln_kernel<<<8192, 256, 0, stream>>>(BN, 512, nullptr, 0, F[21], F[22],
                                        out0, 512, nullptr, 0);
    // out1 = sigmoid(cat@M4+b4) * (cat@M5+b5)                -> d_out+4M
    gemm_bf2<<<dim3(16, 64), 256, 0, stream>>>(
        CB, 1024, MT[4], MT[5], 1024, F[15], F[18], out1, 1024, 1024);
}